// Round 9
// baseline (537.183 us; speedup 1.0000x reference)
//
#include <hip/hip_runtime.h>
#include <hip/hip_bf16.h>

typedef __hip_bfloat16 bf16;
typedef short bf16x8 __attribute__((ext_vector_type(8)));
typedef float f32x4 __attribute__((ext_vector_type(4)));

#define N_NODES 100000
#define N_EDGES 3200000
#define N_GRAPHS 512
#define NBKT    ((N_NODES + 255) / 256)               // 391 buckets of 256 nodes
#define CAP     10496                                 // slots per bucket window (8-aligned)
#define EPB     8192                                  // edges per k_bucket block
#define NBLK_A  ((N_EDGES + EPB - 1) / EPB)           // 391
#define FP8_SCALE 64.0f
#define FP8_INV   (1.0f / 64.0f)

// ---------- fp8 e4m3 helpers (OCP on gfx950) ----------

__device__ inline unsigned char f32_to_fp8(float v) {
#if __has_builtin(__builtin_amdgcn_cvt_pk_fp8_f32)
    return (unsigned char)(__builtin_amdgcn_cvt_pk_fp8_f32(v, v, 0, 0) & 0xFF);
#else
    unsigned u = __float_as_uint(v);
    unsigned s = (u >> 24) & 0x80;
    float a = fabsf(v);
    if (a < 9.765625e-4f) return (unsigned char)s;
    if (a >= 448.f) return (unsigned char)(s | 0x7E);
    if (a < 0.015625f) {
        int mm = (int)(a * 512.f + 0.5f);
        if (mm > 7) mm = 7;
        return (unsigned char)(s | mm);
    }
    unsigned keep = (u >> 20) & 1;
    u = (u & 0x7FFFFFFF) + 0x7FFFF + keep;
    unsigned e = ((u >> 23) & 0xFF) - 120;
    if (e > 15) { e = 15; return (unsigned char)(s | 0x7E); }
    return (unsigned char)(s | (e << 3) | ((u >> 20) & 7));
#endif
}

__device__ inline unsigned pack4_fp8(float o0, float o1, float o2, float o3) {
#if __has_builtin(__builtin_amdgcn_cvt_pk_fp8_f32)
    unsigned d = 0;
    d = (unsigned)__builtin_amdgcn_cvt_pk_fp8_f32(o0, o1, (int)d, 0);
    d = (unsigned)__builtin_amdgcn_cvt_pk_fp8_f32(o2, o3, (int)d, 1);
    return d;
#else
    return (unsigned)f32_to_fp8(o0) | ((unsigned)f32_to_fp8(o1) << 8) |
           ((unsigned)f32_to_fp8(o2) << 16) | ((unsigned)f32_to_fp8(o3) << 24);
#endif
}

__device__ inline float fp8_to_f32(unsigned int b) {
    unsigned s = (b >> 7) & 1, e = (b >> 3) & 15, m = b & 7;
    float v = (e == 0) ? (float)m * 0.001953125f
                       : __uint_as_float(((e + 120u) << 23) | (m << 20));
    return s ? -v : v;
}

__device__ inline void acc4(float* a, unsigned v) {
#if __has_builtin(__builtin_amdgcn_cvt_pk_f32_fp8)
    typedef float f32x2 __attribute__((ext_vector_type(2)));
    f32x2 lo = __builtin_amdgcn_cvt_pk_f32_fp8((int)v, false);
    f32x2 hi = __builtin_amdgcn_cvt_pk_f32_fp8((int)v, true);
    a[0] += lo.x; a[1] += lo.y; a[2] += hi.x; a[3] += hi.y;
#elif __has_builtin(__builtin_amdgcn_cvt_f32_fp8)
    a[0] += __builtin_amdgcn_cvt_f32_fp8(v, 0);
    a[1] += __builtin_amdgcn_cvt_f32_fp8(v, 1);
    a[2] += __builtin_amdgcn_cvt_f32_fp8(v, 2);
    a[3] += __builtin_amdgcn_cvt_f32_fp8(v, 3);
#else
    a[0] += fp8_to_f32(v & 0xFF);
    a[1] += fp8_to_f32((v >> 8) & 0xFF);
    a[2] += fp8_to_f32((v >> 16) & 0xFF);
    a[3] += fp8_to_f32((v >> 24) & 0xFF);
#endif
}

__device__ inline unsigned short f2bf(float x) {
    unsigned u = __float_as_uint(x);
    return (unsigned short)((u + 0x7FFF + ((u >> 16) & 1)) >> 16);
}

// ---------- init per-bucket cursors to window bases ----------

__global__ void k_ginit(int* __restrict__ gcur) {
    int b = blockIdx.x * blockDim.x + threadIdx.x;
    if (b < NBKT) gcur[b] = b * CAP;
}

// ---------- Pass A: bin edges by dst>>8 into fixed-CAP bucket windows ----------

__global__ void __launch_bounds__(256) k_bucket(const int* __restrict__ ei,
                                                int* __restrict__ gcur,
                                                int* __restrict__ ebuf) {
    __shared__ int cnt[NBKT];
    __shared__ int base[NBKT];
    int t = threadIdx.x;
    for (int i = t; i < NBKT; i += 256) cnt[i] = 0;
    __syncthreads();
    int e0 = blockIdx.x * EPB + t;
    int sv[32], dv[32];
    #pragma unroll
    for (int j = 0; j < 32; ++j) {
        int e = e0 + j * 256;
        if (e < N_EDGES) {
            sv[j] = ei[e];
            dv[j] = ei[N_EDGES + e];
            atomicAdd(&cnt[dv[j] >> 8], 1);
        } else dv[j] = -1;
    }
    __syncthreads();
    for (int i = t; i < NBKT; i += 256) {
        base[i] = atomicAdd(&gcur[i], cnt[i]);
        cnt[i] = 0;
    }
    __syncthreads();
    #pragma unroll
    for (int j = 0; j < 32; ++j) {
        if (dv[j] >= 0) {
            int b = dv[j] >> 8;
            int r = atomicAdd(&cnt[b], 1);
            ebuf[base[b] + r] = (sv[j] << 8) | (dv[j] & 255);
        }
    }
}

// ---------- Pass B: per-bucket histogram -> rc/dis, 8-aligned col, pad-gap dummies ----------

__global__ void __launch_bounds__(256) k_fill2(const int* __restrict__ ebuf,
                                               const int* __restrict__ gcur,
                                               int2* __restrict__ rc,
                                               float* __restrict__ dis,
                                               int* __restrict__ col) {
    __shared__ int cnt[256];
    __shared__ int sc[256];
    __shared__ int exs[256];
    __shared__ int cur[256];
    int b = blockIdx.x, t = threadIdx.x;
    int n0 = b * 256;
    int nrec = gcur[b] - b * CAP;
    const int* eb = ebuf + (size_t)b * CAP;
    int* cw = col + (size_t)b * CAP;
    cnt[t] = 0; cur[t] = 0;
    __syncthreads();
    for (int i = t; i < nrec; i += 256)
        atomicAdd(&cnt[eb[i] & 255], 1);
    __syncthreads();
    int c0 = cnt[t];
    int a8 = (c0 + 7) & ~7;
    sc[t] = a8; __syncthreads();
    for (int off = 1; off < 256; off <<= 1) {
        int u = (t >= off) ? sc[t - off] : 0;
        __syncthreads();
        sc[t] += u;
        __syncthreads();
    }
    int myex = sc[t] - a8;
    exs[t] = myex;
    int n = n0 + t;
    if (n < N_NODES) {
        rc[n] = make_int2(b * CAP + myex, c0);
        dis[n] = rsqrtf((float)(c0 + 1));
    }
    // fill only the 8-align padding gap of this thread's node with dummies
    for (int i = myex + c0; i < myex + a8; ++i) cw[i] = N_NODES;
    __syncthreads();
    for (int i = t; i < nrec; i += 256) {
        int rec = eb[i];
        int dl = rec & 255;
        cw[exs[dl] + atomicAdd(&cur[dl], 1)] = rec >> 8;
    }
}

// ---------- folded embedding weight: Wc = W_emb@W1, bc = b_emb@W1 ----------

__global__ void k_wc(const float* __restrict__ W_emb, const float* __restrict__ b_emb,
                     const float* __restrict__ W1, float* __restrict__ Wc,
                     float* __restrict__ bc) {
    int t = threadIdx.x;
    for (int i = t; i < 32 * 64; i += 256) {
        int a = i / 64, b = i % 64;
        float acc = 0.f;
        for (int k = 0; k < 64; ++k) acc += W_emb[a * 64 + k] * W1[k * 64 + b];
        Wc[i] = acc;
    }
    if (t < 64) {
        float acc = 0.f;
        for (int k = 0; k < 64; ++k) acc += b_emb[k] * W1[k * 64 + t];
        bc[t] = acc;
    }
}

// ---------- Wn -> per-lane MFMA A-fragment layout (A = Wn^T), bf16 ----------

__global__ void k_wprep(const float* __restrict__ W2, const float* __restrict__ W3,
                        const float* __restrict__ W4, unsigned short* __restrict__ Wfrag) {
    const float* W = (blockIdx.x == 0) ? W2 : (blockIdx.x == 1) ? W3 : W4;
    unsigned short* dst = Wfrag + (size_t)blockIdx.x * 4096;
    int t = threadIdx.x;
    for (int i = 0; i < 16; ++i) {
        int flat = t * 16 + i;
        int j = flat & 7, lane = (flat >> 3) & 63, mt = (flat >> 9) & 3, kt = flat >> 11;
        int m = mt * 16 + (lane & 15);
        int k = kt * 32 + ((lane >> 4) << 3) + j;
        dst[flat] = f2bf(W[k * 64 + m]);
    }
}

// ---------- layer-1 matmul -> split fp8 half-tables ----------

__global__ void __launch_bounds__(256) k_mm1(const float* __restrict__ inp,
                                             const float* __restrict__ W,
                                             const float* __restrict__ bias,
                                             const float* __restrict__ dis,
                                             unsigned char* __restrict__ tA,
                                             unsigned char* __restrict__ tB) {
    __shared__ float Wl[32][64];
    __shared__ float hs[16][32];
    int t = threadIdx.x;
    for (int i = t; i < 32 * 64; i += 256) Wl[i / 64][i % 64] = W[i];
    int row0 = blockIdx.x * 16;
    for (int i = t; i < 16 * 32; i += 256) {
        int r = row0 + i / 32, k = i % 32;
        hs[i / 32][k] = inp[(size_t)r * 32 + k];
    }
    __syncthreads();
    int c = t & 63, rg = t >> 6;
    float a0 = 0, a1 = 0, a2 = 0, a3 = 0;
    #pragma unroll 4
    for (int k = 0; k < 32; ++k) {
        float wv = Wl[k][c];
        a0 += hs[rg * 4 + 0][k] * wv;
        a1 += hs[rg * 4 + 1][k] * wv;
        a2 += hs[rg * 4 + 2][k] * wv;
        a3 += hs[rg * 4 + 3][k] * wv;
    }
    float bv = bias[c];
    int r = row0 + rg * 4;
    unsigned char* dst = (c < 32) ? tA : tB;
    int cc = c & 31;
    dst[(size_t)(r + 0) * 32 + cc] = f32_to_fp8(FP8_SCALE * dis[r + 0] * (a0 + bv));
    dst[(size_t)(r + 1) * 32 + cc] = f32_to_fp8(FP8_SCALE * dis[r + 1] * (a1 + bv));
    dst[(size_t)(r + 2) * 32 + cc] = f32_to_fp8(FP8_SCALE * dis[r + 2] * (a2 + bv));
    dst[(size_t)(r + 3) * 32 + cc] = f32_to_fp8(FP8_SCALE * dis[r + 3] * (a3 + bv));
}

// ---------- AGG v3: one wave per dst row; 64 lanes = 8 edge-slots x 8 feature-dwords ----------
// agg[row, 32 feats] = tph[row] + sum_e tph[col[e]]   (bf16 out)

__global__ void __launch_bounds__(256) k_agg(const unsigned* __restrict__ tph,
                                             const int2* __restrict__ rc,
                                             const int* __restrict__ col,
                                             unsigned short* __restrict__ agg) {
    int lane = threadIdx.x & 63;
    int g = lane >> 3;                   // edge-slot 0..7
    int sl = lane & 7;                   // feature dword 0..7
    int row = blockIdx.x * 4 + (threadIdx.x >> 6);
    int2 r = rc[row];
    const int* cp = col + r.x + g;
    int deg8 = (r.y + 7) & ~7;
    float a[4] = {0.f, 0.f, 0.f, 0.f};
    for (int p = 0; p < deg8; p += 8) {
        int c = cp[p];                   // 8 lanes of a slot share one address (broadcast)
        acc4(a, tph[(size_t)c * 8 + sl]);
    }
    #pragma unroll
    for (int off = 8; off < 64; off <<= 1) {
        a[0] += __shfl_xor(a[0], off);
        a[1] += __shfl_xor(a[1], off);
        a[2] += __shfl_xor(a[2], off);
        a[3] += __shfl_xor(a[3], off);
    }
    if (g == 0) {
        acc4(a, tph[(size_t)row * 8 + sl]);    // self-loop term
        ushort4 o;
        o.x = f2bf(a[0]); o.y = f2bf(a[1]); o.z = f2bf(a[2]); o.w = f2bf(a[3]);
        *(ushort4*)(agg + (size_t)row * 32 + sl * 4) = o;
    }
}

// ---------- MFMA COMBINE: h = relu(dis/S*agg + b); next halves = fp8(S*dis*(h@Wn)) ----------

__global__ void __launch_bounds__(256) k_combm(const unsigned short* __restrict__ aggA,
                                               const unsigned short* __restrict__ aggB,
                                               const float* __restrict__ dis,
                                               const float* __restrict__ bias,
                                               const unsigned short* __restrict__ Wfrag,
                                               unsigned* __restrict__ tA,
                                               unsigned* __restrict__ tB) {
    __shared__ unsigned short h_lds[64][72];          // bf16, padded stride
    int t = threadIdx.x;
    int rowbase = blockIdx.x * 64;
    {
        int row = t >> 2, q = t & 3;
        int grow = rowbase + row;
        if (grow < N_NODES) {
            float f = dis[grow] * FP8_INV;
            #pragma unroll
            for (int i = 0; i < 4; ++i) {
                int c0 = q * 16 + i * 4;
                const unsigned short* src = ((c0 < 32) ? aggA : aggB) +
                                            (size_t)grow * 32 + (c0 & 31);
                ushort4 v = *(const ushort4*)src;
                short4 o;
                o.x = (short)f2bf(fmaxf(f * __uint_as_float((unsigned)v.x << 16) + bias[c0 + 0], 0.f));
                o.y = (short)f2bf(fmaxf(f * __uint_as_float((unsigned)v.y << 16) + bias[c0 + 1], 0.f));
                o.z = (short)f2bf(fmaxf(f * __uint_as_float((unsigned)v.z << 16) + bias[c0 + 2], 0.f));
                o.w = (short)f2bf(fmaxf(f * __uint_as_float((unsigned)v.w << 16) + bias[c0 + 3], 0.f));
                *(short4*)&h_lds[row][c0] = o;
            }
        } else {
            #pragma unroll
            for (int i = 0; i < 4; ++i)
                *(short4*)&h_lds[row][q * 16 + i * 4] = make_short4(0, 0, 0, 0);
        }
    }
    __syncthreads();
    int w = t >> 6, l = t & 63;
    f32x4 acc[4] = {{0,0,0,0}, {0,0,0,0}, {0,0,0,0}, {0,0,0,0}};
    const bf16x8* wf = (const bf16x8*)Wfrag;
    #pragma unroll
    for (int kt = 0; kt < 2; ++kt) {
        bf16x8 bfr = *(const bf16x8*)&h_lds[w * 16 + (l & 15)][kt * 32 + ((l >> 4) << 3)];
        #pragma unroll
        for (int mt = 0; mt < 4; ++mt) {
            bf16x8 afr = wf[(kt * 4 + mt) * 64 + l];
            acc[mt] = __builtin_amdgcn_mfma_f32_16x16x32_bf16(afr, bfr, acc[mt], 0, 0, 0);
        }
    }
    int hrow = rowbase + w * 16 + (l & 15);
    if (hrow < N_NODES) {
        float sc2 = FP8_SCALE * dis[hrow];
        #pragma unroll
        for (int mt = 0; mt < 4; ++mt) {
            int colbase = mt * 16 + ((l >> 4) << 2);
            unsigned d = pack4_fp8(sc2 * acc[mt][0], sc2 * acc[mt][1],
                                   sc2 * acc[mt][2], sc2 * acc[mt][3]);
            if (colbase < 32) tA[(size_t)hrow * 8 + (colbase >> 2)] = d;
            else              tB[(size_t)hrow * 8 + ((colbase - 32) >> 2)] = d;
        }
    }
}

// ---------- last-layer combine: h (bf16) only ----------

__global__ void __launch_bounds__(256) k_combl(const unsigned short* __restrict__ aggA,
                                               const unsigned short* __restrict__ aggB,
                                               const float* __restrict__ dis,
                                               const float* __restrict__ bias,
                                               unsigned short* __restrict__ h) {
    int t = threadIdx.x;
    int row = blockIdx.x * 16 + (t >> 4);
    int sl = t & 15;
    int slh = sl & 7;
    const unsigned short* ag = (sl < 8) ? aggA : aggB;
    ushort4 av = *(const ushort4*)(ag + (size_t)row * 32 + slh * 4);
    float s = dis[row] * FP8_INV;
    ushort4 hv;
    hv.x = f2bf(fmaxf(s * __uint_as_float((unsigned)av.x << 16) + bias[sl * 4 + 0], 0.f));
    hv.y = f2bf(fmaxf(s * __uint_as_float((unsigned)av.y << 16) + bias[sl * 4 + 1], 0.f));
    hv.z = f2bf(fmaxf(s * __uint_as_float((unsigned)av.z << 16) + bias[sl * 4 + 2], 0.f));
    hv.w = f2bf(fmaxf(s * __uint_as_float((unsigned)av.w << 16) + bias[sl * 4 + 3], 0.f));
    *(ushort4*)(h + (size_t)row * 64 + sl * 4) = hv;
}

// ---------- global mean pool: one block per graph, batch sorted ----------

__global__ void __launch_bounds__(256) k_pool(const unsigned short* __restrict__ h,
                                              const int* __restrict__ batch,
                                              float* __restrict__ pooled) {
    __shared__ float part[4][64];
    __shared__ int seg[2];
    int g = blockIdx.x, t = threadIdx.x;
    if (t < 2) {
        int key = g + t;
        int lo = 0, hi = N_NODES;
        while (lo < hi) { int m = (lo + hi) >> 1; if (batch[m] < key) lo = m + 1; else hi = m; }
        seg[t] = lo;
    }
    __syncthreads();
    int start = seg[0], end = seg[1];
    int w = t >> 6, grp = (t >> 4) & 3, sl = t & 15;
    float a[4] = {0.f, 0.f, 0.f, 0.f};
    for (int r = start + w * 4 + grp; r < end; r += 16) {
        ushort4 v = *(const ushort4*)(h + (size_t)r * 64 + sl * 4);
        a[0] += __uint_as_float((unsigned)v.x << 16);
        a[1] += __uint_as_float((unsigned)v.y << 16);
        a[2] += __uint_as_float((unsigned)v.z << 16);
        a[3] += __uint_as_float((unsigned)v.w << 16);
    }
    #pragma unroll
    for (int j = 0; j < 4; ++j) {
        a[j] += __shfl_xor(a[j], 16);
        a[j] += __shfl_xor(a[j], 32);
    }
    if (sl == (t & 63)) {
        #pragma unroll
        for (int j = 0; j < 4; ++j) part[w][sl * 4 + j] = a[j];
    }
    __syncthreads();
    if (t < 64) {
        float s = part[0][t] + part[1][t] + part[2][t] + part[3][t];
        float c = fmaxf((float)(end - start), 1.f);
        pooled[g * 64 + t] = s / c;
    }
}

// ---------- readout MLP + log_softmax ----------

__global__ void k_head(const float* __restrict__ pooled,
                       const float* __restrict__ Wr1, const float* __restrict__ br1,
                       const float* __restrict__ Wr2, const float* __restrict__ br2,
                       const float* __restrict__ Wr3, const float* __restrict__ br3,
                       float* __restrict__ out) {
    int g = blockIdx.x, t = threadIdx.x;  // 64 threads
    __shared__ float p[64], r1[32], r2[16], lg[10];
    p[t] = pooled[g * 64 + t];
    __syncthreads();
    if (t < 32) {
        float a = br1[t];
        for (int k = 0; k < 64; ++k) a += p[k] * Wr1[k * 32 + t];
        r1[t] = fmaxf(a, 0.f);
    }
    __syncthreads();
    if (t < 16) {
        float a = br2[t];
        for (int k = 0; k < 32; ++k) a += r1[k] * Wr2[k * 16 + t];
        r2[t] = fmaxf(a, 0.f);
    }
    __syncthreads();
    if (t < 10) {
        float a = br3[t];
        for (int k = 0; k < 16; ++k) a += r2[k] * Wr3[k * 10 + t];
        lg[t] = a;
    }
    __syncthreads();
    if (t < 10) {
        float m = -1e30f;
        for (int j = 0; j < 10; ++j) m = fmaxf(m, lg[j]);
        float s = 0.f;
        for (int j = 0; j < 10; ++j) s += expf(lg[j] - m);
        out[g * 10 + t] = lg[t] - m - logf(s);
    }
}

extern "C" void kernel_launch(void* const* d_in, const int* in_sizes, int n_in,
                              void* d_out, int out_size, void* d_ws, size_t ws_size,
                              hipStream_t stream) {
    const float* x     = (const float*)d_in[0];
    const int*   ei    = (const int*)d_in[1];
    const int*   batch = (const int*)d_in[2];
    const float* W_emb = (const float*)d_in[4];
    const float* b_emb = (const float*)d_in[5];
    const float* W1    = (const float*)d_in[6];
    const float* b1    = (const float*)d_in[7];
    const float* W2    = (const float*)d_in[8];
    const float* b2    = (const float*)d_in[9];
    const float* W3    = (const float*)d_in[10];
    const float* b3    = (const float*)d_in[11];
    const float* W4    = (const float*)d_in[12];
    const float* b4    = (const float*)d_in[13];
    const float* Wr1   = (const float*)d_in[14];
    const float* br1   = (const float*)d_in[15];
    const float* Wr2   = (const float*)d_in[16];
    const float* br2   = (const float*)d_in[17];
    const float* Wr3   = (const float*)d_in[18];
    const float* br3   = (const float*)d_in[19];
    float* out = (float*)d_out;

    char* ws = (char*)d_ws;
    size_t off = 0;
    auto alloc = [&](size_t b) { char* p = ws + off; off += (b + 511) & ~(size_t)511; return p; };
    size_t TBYTES = (size_t)(N_NODES + 1) * 32;
    int*   col    = (int*)  alloc((size_t)NBKT * CAP * 4);     // 16.4 MB
    char*  ebufh  =         alloc((size_t)NBKT * CAP * 4);     // ebuf, later reused as h
    unsigned char* T0a = (unsigned char*)alloc(TBYTES);        // fp8 half-tables (+dummy row)
    unsigned char* T0b = (unsigned char*)alloc(TBYTES);
    unsigned char* T1a = (unsigned char*)alloc(TBYTES);
    unsigned char* T1b = (unsigned char*)alloc(TBYTES);
    unsigned short* aggA = (unsigned short*)alloc((size_t)N_NODES * 32 * 2);  // bf16
    unsigned short* aggB = (unsigned short*)alloc((size_t)N_NODES * 32 * 2);
    int2*  rc     = (int2*) alloc((size_t)N_NODES * 8);
    float* dis    = (float*)alloc((size_t)N_NODES * 4);
    int*   gcur   = (int*)  alloc((size_t)NBKT * 4);
    float* Wc     = (float*)alloc(32 * 64 * 4);
    float* bc     = (float*)alloc(64 * 4);
    unsigned short* Wfrag = (unsigned short*)alloc(3 * 4096 * 2);
    float* pooled = (float*)alloc((size_t)N_GRAPHS * 64 * 4);

    int* ebuf = (int*)ebufh;
    unsigned short* hbuf = (unsigned short*)ebufh;   // alias: h lives where ebuf was

    hipMemsetAsync(T0a + (size_t)N_NODES * 32, 0, 32, stream);
    hipMemsetAsync(T0b + (size_t)N_NODES * 32, 0, 32, stream);
    hipMemsetAsync(T1a + (size_t)N_NODES * 32, 0, 32, stream);
    hipMemsetAsync(T1b + (size_t)N_NODES * 32, 0, 32, stream);

    k_ginit<<<(NBKT + 255) / 256, 256, 0, stream>>>(gcur);
    k_bucket<<<NBLK_A, 256, 0, stream>>>(ei, gcur, ebuf);
    k_fill2<<<NBKT, 256, 0, stream>>>(ebuf, gcur, rc, dis, col);
    k_wc<<<1, 256, 0, stream>>>(W_emb, b_emb, W1, Wc, bc);
    k_wprep<<<3, 256, 0, stream>>>(W2, W3, W4, Wfrag);

    int nbm = N_NODES / 16;        // 6250
    int nbw = N_NODES / 4;         // 25000 (one wave per row)
    int nbc = (N_NODES + 63) / 64; // 1563

    k_mm1<<<nbm, 256, 0, stream>>>(x, Wc, bc, dis, T0a, T0b);

    const float* lb[4] = {b1, b2, b3, b4};
    unsigned char* cura = T0a; unsigned char* curb = T0b;
    unsigned char* nxta = T1a; unsigned char* nxtb = T1b;
    for (int l = 0; l < 4; ++l) {
        k_agg<<<nbw, 256, 0, stream>>>((const unsigned*)cura, rc, col, aggA);
        k_agg<<<nbw, 256, 0, stream>>>((const unsigned*)curb, rc, col, aggB);
        if (l < 3) {
            k_combm<<<nbc, 256, 0, stream>>>(aggA, aggB, dis, lb[l], Wfrag + (size_t)l * 4096,
                                             (unsigned*)nxta, (unsigned*)nxtb);
            unsigned char* ta = cura; cura = nxta; nxta = ta;
            unsigned char* tb = curb; curb = nxtb; nxtb = tb;
        } else {
            k_combl<<<nbm, 256, 0, stream>>>(aggA, aggB, dis, lb[l], hbuf);
        }
    }

    k_pool<<<N_GRAPHS, 256, 0, stream>>>(hbuf, batch, pooled);
    k_head<<<N_GRAPHS, 64, 0, stream>>>(pooled, Wr1, br1, Wr2, br2, Wr3, br3, out);
}

// Round 10
// 339.932 us; speedup vs baseline: 1.5803x; 1.5803x over previous
//
#include <hip/hip_runtime.h>
#include <hip/hip_bf16.h>

typedef __hip_bfloat16 bf16;
typedef short bf16x8 __attribute__((ext_vector_type(8)));
typedef float f32x4 __attribute__((ext_vector_type(4)));

#define N_NODES 100000
#define N_EDGES 3200000
#define N_GRAPHS 512
#define NBKT    ((N_NODES + 255) / 256)               // 391 buckets of 256 nodes
#define CAP     11776                                 // slots per bucket window (16-aligned)
#define EPB     8192                                  // edges per k_bucket block
#define NBLK_A  ((N_EDGES + EPB - 1) / EPB)           // 391
#define FP8_SCALE 64.0f
#define FP8_INV   (1.0f / 64.0f)

// ---------- fp8 e4m3 helpers (OCP on gfx950) ----------

__device__ inline unsigned char f32_to_fp8(float v) {
#if __has_builtin(__builtin_amdgcn_cvt_pk_fp8_f32)
    return (unsigned char)(__builtin_amdgcn_cvt_pk_fp8_f32(v, v, 0, 0) & 0xFF);
#else
    unsigned u = __float_as_uint(v);
    unsigned s = (u >> 24) & 0x80;
    float a = fabsf(v);
    if (a < 9.765625e-4f) return (unsigned char)s;
    if (a >= 448.f) return (unsigned char)(s | 0x7E);
    if (a < 0.015625f) {
        int mm = (int)(a * 512.f + 0.5f);
        if (mm > 7) mm = 7;
        return (unsigned char)(s | mm);
    }
    unsigned keep = (u >> 20) & 1;
    u = (u & 0x7FFFFFFF) + 0x7FFFF + keep;
    unsigned e = ((u >> 23) & 0xFF) - 120;
    if (e > 15) { e = 15; return (unsigned char)(s | 0x7E); }
    return (unsigned char)(s | (e << 3) | ((u >> 20) & 7));
#endif
}

__device__ inline unsigned pack4_fp8(float o0, float o1, float o2, float o3) {
#if __has_builtin(__builtin_amdgcn_cvt_pk_fp8_f32)
    unsigned d = 0;
    d = (unsigned)__builtin_amdgcn_cvt_pk_fp8_f32(o0, o1, (int)d, 0);
    d = (unsigned)__builtin_amdgcn_cvt_pk_fp8_f32(o2, o3, (int)d, 1);
    return d;
#else
    return (unsigned)f32_to_fp8(o0) | ((unsigned)f32_to_fp8(o1) << 8) |
           ((unsigned)f32_to_fp8(o2) << 16) | ((unsigned)f32_to_fp8(o3) << 24);
#endif
}

__device__ inline float fp8_to_f32(unsigned int b) {
    unsigned s = (b >> 7) & 1, e = (b >> 3) & 15, m = b & 7;
    float v = (e == 0) ? (float)m * 0.001953125f
                       : __uint_as_float(((e + 120u) << 23) | (m << 20));
    return s ? -v : v;
}

__device__ inline void acc4(float* a, unsigned v) {
#if __has_builtin(__builtin_amdgcn_cvt_pk_f32_fp8)
    typedef float f32x2 __attribute__((ext_vector_type(2)));
    f32x2 lo = __builtin_amdgcn_cvt_pk_f32_fp8((int)v, false);
    f32x2 hi = __builtin_amdgcn_cvt_pk_f32_fp8((int)v, true);
    a[0] += lo.x; a[1] += lo.y; a[2] += hi.x; a[3] += hi.y;
#elif __has_builtin(__builtin_amdgcn_cvt_f32_fp8)
    a[0] += __builtin_amdgcn_cvt_f32_fp8(v, 0);
    a[1] += __builtin_amdgcn_cvt_f32_fp8(v, 1);
    a[2] += __builtin_amdgcn_cvt_f32_fp8(v, 2);
    a[3] += __builtin_amdgcn_cvt_f32_fp8(v, 3);
#else
    a[0] += fp8_to_f32(v & 0xFF);
    a[1] += fp8_to_f32((v >> 8) & 0xFF);
    a[2] += fp8_to_f32((v >> 16) & 0xFF);
    a[3] += fp8_to_f32((v >> 24) & 0xFF);
#endif
}

__device__ inline unsigned short f2bf(float x) {
    unsigned u = __float_as_uint(x);
    return (unsigned short)((u + 0x7FFF + ((u >> 16) & 1)) >> 16);
}

// ---------- init per-bucket cursors to window bases ----------

__global__ void k_ginit(int* __restrict__ gcur) {
    int b = blockIdx.x * blockDim.x + threadIdx.x;
    if (b < NBKT) gcur[b] = b * CAP;
}

// ---------- Pass A: bin edges by dst>>8 into fixed-CAP bucket windows ----------

__global__ void __launch_bounds__(256) k_bucket(const int* __restrict__ ei,
                                                int* __restrict__ gcur,
                                                int* __restrict__ ebuf) {
    __shared__ int cnt[NBKT];
    __shared__ int base[NBKT];
    int t = threadIdx.x;
    for (int i = t; i < NBKT; i += 256) cnt[i] = 0;
    __syncthreads();
    int e0 = blockIdx.x * EPB + t;
    int sv[32], dv[32];
    #pragma unroll
    for (int j = 0; j < 32; ++j) {
        int e = e0 + j * 256;
        if (e < N_EDGES) {
            sv[j] = ei[e];
            dv[j] = ei[N_EDGES + e];
            atomicAdd(&cnt[dv[j] >> 8], 1);
        } else dv[j] = -1;
    }
    __syncthreads();
    for (int i = t; i < NBKT; i += 256) {
        base[i] = atomicAdd(&gcur[i], cnt[i]);
        cnt[i] = 0;
    }
    __syncthreads();
    #pragma unroll
    for (int j = 0; j < 32; ++j) {
        if (dv[j] >= 0) {
            int b = dv[j] >> 8;
            int r = atomicAdd(&cnt[b], 1);
            ebuf[base[b] + r] = (sv[j] << 8) | (dv[j] & 255);
        }
    }
}

// ---------- Pass B: per-bucket histogram -> rc/dis, 16-aligned col, pad-gap dummies ----------

__global__ void __launch_bounds__(256) k_fill2(const int* __restrict__ ebuf,
                                               const int* __restrict__ gcur,
                                               int2* __restrict__ rc,
                                               float* __restrict__ dis,
                                               int* __restrict__ col) {
    __shared__ int cnt[256];
    __shared__ int sc[256];
    __shared__ int exs[256];
    __shared__ int cur[256];
    int b = blockIdx.x, t = threadIdx.x;
    int n0 = b * 256;
    int nrec = gcur[b] - b * CAP;
    const int* eb = ebuf + (size_t)b * CAP;
    int* cw = col + (size_t)b * CAP;
    cnt[t] = 0; cur[t] = 0;
    __syncthreads();
    for (int i = t; i < nrec; i += 256)
        atomicAdd(&cnt[eb[i] & 255], 1);
    __syncthreads();
    int c0 = cnt[t];
    int a16 = (c0 + 15) & ~15;
    sc[t] = a16; __syncthreads();
    for (int off = 1; off < 256; off <<= 1) {
        int u = (t >= off) ? sc[t - off] : 0;
        __syncthreads();
        sc[t] += u;
        __syncthreads();
    }
    int myex = sc[t] - a16;
    exs[t] = myex;
    int n = n0 + t;
    if (n < N_NODES) {
        rc[n] = make_int2(b * CAP + myex, c0);
        dis[n] = rsqrtf((float)(c0 + 1));
    }
    // fill only the 16-align padding gap of this thread's node with dummies
    for (int i = myex + c0; i < myex + a16; ++i) cw[i] = N_NODES;
    __syncthreads();
    for (int i = t; i < nrec; i += 256) {
        int rec = eb[i];
        int dl = rec & 255;
        cw[exs[dl] + atomicAdd(&cur[dl], 1)] = rec >> 8;
    }
}

// ---------- folded embedding weight: Wc = W_emb@W1, bc = b_emb@W1 ----------

__global__ void k_wc(const float* __restrict__ W_emb, const float* __restrict__ b_emb,
                     const float* __restrict__ W1, float* __restrict__ Wc,
                     float* __restrict__ bc) {
    int t = threadIdx.x;
    for (int i = t; i < 32 * 64; i += 256) {
        int a = i / 64, b = i % 64;
        float acc = 0.f;
        for (int k = 0; k < 64; ++k) acc += W_emb[a * 64 + k] * W1[k * 64 + b];
        Wc[i] = acc;
    }
    if (t < 64) {
        float acc = 0.f;
        for (int k = 0; k < 64; ++k) acc += b_emb[k] * W1[k * 64 + t];
        bc[t] = acc;
    }
}

// ---------- Wn -> per-lane MFMA A-fragment layout (A = Wn^T), bf16 ----------

__global__ void k_wprep(const float* __restrict__ W2, const float* __restrict__ W3,
                        const float* __restrict__ W4, unsigned short* __restrict__ Wfrag) {
    const float* W = (blockIdx.x == 0) ? W2 : (blockIdx.x == 1) ? W3 : W4;
    unsigned short* dst = Wfrag + (size_t)blockIdx.x * 4096;
    int t = threadIdx.x;
    for (int i = 0; i < 16; ++i) {
        int flat = t * 16 + i;
        int j = flat & 7, lane = (flat >> 3) & 63, mt = (flat >> 9) & 3, kt = flat >> 11;
        int m = mt * 16 + (lane & 15);
        int k = kt * 32 + ((lane >> 4) << 3) + j;
        dst[flat] = f2bf(W[k * 64 + m]);
    }
}

// ---------- layer-1 matmul -> split fp8 half-tables ----------

__global__ void __launch_bounds__(256) k_mm1(const float* __restrict__ inp,
                                             const float* __restrict__ W,
                                             const float* __restrict__ bias,
                                             const float* __restrict__ dis,
                                             unsigned char* __restrict__ tA,
                                             unsigned char* __restrict__ tB) {
    __shared__ float Wl[32][64];
    __shared__ float hs[16][32];
    int t = threadIdx.x;
    for (int i = t; i < 32 * 64; i += 256) Wl[i / 64][i % 64] = W[i];
    int row0 = blockIdx.x * 16;
    for (int i = t; i < 16 * 32; i += 256) {
        int r = row0 + i / 32, k = i % 32;
        hs[i / 32][k] = inp[(size_t)r * 32 + k];
    }
    __syncthreads();
    int c = t & 63, rg = t >> 6;
    float a0 = 0, a1 = 0, a2 = 0, a3 = 0;
    #pragma unroll 4
    for (int k = 0; k < 32; ++k) {
        float wv = Wl[k][c];
        a0 += hs[rg * 4 + 0][k] * wv;
        a1 += hs[rg * 4 + 1][k] * wv;
        a2 += hs[rg * 4 + 2][k] * wv;
        a3 += hs[rg * 4 + 3][k] * wv;
    }
    float bv = bias[c];
    int r = row0 + rg * 4;
    unsigned char* dst = (c < 32) ? tA : tB;
    int cc = c & 31;
    dst[(size_t)(r + 0) * 32 + cc] = f32_to_fp8(FP8_SCALE * dis[r + 0] * (a0 + bv));
    dst[(size_t)(r + 1) * 32 + cc] = f32_to_fp8(FP8_SCALE * dis[r + 1] * (a1 + bv));
    dst[(size_t)(r + 2) * 32 + cc] = f32_to_fp8(FP8_SCALE * dis[r + 2] * (a2 + bv));
    dst[(size_t)(r + 3) * 32 + cc] = f32_to_fp8(FP8_SCALE * dis[r + 3] * (a3 + bv));
}

// ---------- AGG v4: 8 rows/wave x 8 feature-dwords, 16 gathers in flight,
//            double-buffered col loads (latency-hiding) ----------
// agg[row, 32 feats] = tph[row] + sum_e tph[col[e]]   (bf16 out)

__global__ void __launch_bounds__(256) k_agg(const unsigned* __restrict__ tph,
                                             const int2* __restrict__ rc,
                                             const int* __restrict__ col,
                                             unsigned short* __restrict__ agg) {
    int row = blockIdx.x * 32 + (threadIdx.x >> 3);
    int sl = threadIdx.x & 7;
    float a[4] = {0.f, 0.f, 0.f, 0.f};
    float b[4] = {0.f, 0.f, 0.f, 0.f};
    acc4(a, tph[(size_t)row * 8 + sl]);                // self-loop term
    int2 r = rc[row];
    int nit = (r.y + 15) >> 4;                         // 16-edge iterations
    const int* cp = col + r.x;
    if (nit > 0) {
        int4 c0 = *(const int4*)(cp + 0);
        int4 c1 = *(const int4*)(cp + 4);
        int4 c2 = *(const int4*)(cp + 8);
        int4 c3 = *(const int4*)(cp + 12);
        for (int it = 1; ; ++it) {
            unsigned v0  = tph[(size_t)c0.x * 8 + sl];
            unsigned v1  = tph[(size_t)c0.y * 8 + sl];
            unsigned v2  = tph[(size_t)c0.z * 8 + sl];
            unsigned v3  = tph[(size_t)c0.w * 8 + sl];
            unsigned v4  = tph[(size_t)c1.x * 8 + sl];
            unsigned v5  = tph[(size_t)c1.y * 8 + sl];
            unsigned v6  = tph[(size_t)c1.z * 8 + sl];
            unsigned v7  = tph[(size_t)c1.w * 8 + sl];
            unsigned v8  = tph[(size_t)c2.x * 8 + sl];
            unsigned v9  = tph[(size_t)c2.y * 8 + sl];
            unsigned v10 = tph[(size_t)c2.z * 8 + sl];
            unsigned v11 = tph[(size_t)c2.w * 8 + sl];
            unsigned v12 = tph[(size_t)c3.x * 8 + sl];
            unsigned v13 = tph[(size_t)c3.y * 8 + sl];
            unsigned v14 = tph[(size_t)c3.z * 8 + sl];
            unsigned v15 = tph[(size_t)c3.w * 8 + sl];
            bool more = it < nit;
            int4 n0, n1, n2, n3;
            if (more) {                                // prefetch next 16 cols
                const int* np = cp + it * 16;
                n0 = *(const int4*)(np + 0);
                n1 = *(const int4*)(np + 4);
                n2 = *(const int4*)(np + 8);
                n3 = *(const int4*)(np + 12);
            }
            acc4(a, v0);  acc4(b, v1);  acc4(a, v2);  acc4(b, v3);
            acc4(a, v4);  acc4(b, v5);  acc4(a, v6);  acc4(b, v7);
            acc4(a, v8);  acc4(b, v9);  acc4(a, v10); acc4(b, v11);
            acc4(a, v12); acc4(b, v13); acc4(a, v14); acc4(b, v15);
            if (!more) break;
            c0 = n0; c1 = n1; c2 = n2; c3 = n3;
        }
    }
    ushort4 o;
    o.x = f2bf(a[0] + b[0]); o.y = f2bf(a[1] + b[1]);
    o.z = f2bf(a[2] + b[2]); o.w = f2bf(a[3] + b[3]);
    *(ushort4*)(agg + (size_t)row * 32 + sl * 4) = o;
}

// ---------- MFMA COMBINE: h = relu(dis/S*agg + b); next halves = fp8(S*dis*(h@Wn)) ----------

__global__ void __launch_bounds__(256) k_combm(const unsigned short* __restrict__ aggA,
                                               const unsigned short* __restrict__ aggB,
                                               const float* __restrict__ dis,
                                               const float* __restrict__ bias,
                                               const unsigned short* __restrict__ Wfrag,
                                               unsigned* __restrict__ tA,
                                               unsigned* __restrict__ tB) {
    __shared__ unsigned short h_lds[64][72];          // bf16, padded stride
    int t = threadIdx.x;
    int rowbase = blockIdx.x * 64;
    {
        int row = t >> 2, q = t & 3;
        int grow = rowbase + row;
        if (grow < N_NODES) {
            float f = dis[grow] * FP8_INV;
            #pragma unroll
            for (int i = 0; i < 4; ++i) {
                int c0 = q * 16 + i * 4;
                const unsigned short* src = ((c0 < 32) ? aggA : aggB) +
                                            (size_t)grow * 32 + (c0 & 31);
                ushort4 v = *(const ushort4*)src;
                short4 o;
                o.x = (short)f2bf(fmaxf(f * __uint_as_float((unsigned)v.x << 16) + bias[c0 + 0], 0.f));
                o.y = (short)f2bf(fmaxf(f * __uint_as_float((unsigned)v.y << 16) + bias[c0 + 1], 0.f));
                o.z = (short)f2bf(fmaxf(f * __uint_as_float((unsigned)v.z << 16) + bias[c0 + 2], 0.f));
                o.w = (short)f2bf(fmaxf(f * __uint_as_float((unsigned)v.w << 16) + bias[c0 + 3], 0.f));
                *(short4*)&h_lds[row][c0] = o;
            }
        } else {
            #pragma unroll
            for (int i = 0; i < 4; ++i)
                *(short4*)&h_lds[row][q * 16 + i * 4] = make_short4(0, 0, 0, 0);
        }
    }
    __syncthreads();
    int w = t >> 6, l = t & 63;
    f32x4 acc[4] = {{0,0,0,0}, {0,0,0,0}, {0,0,0,0}, {0,0,0,0}};
    const bf16x8* wf = (const bf16x8*)Wfrag;
    #pragma unroll
    for (int kt = 0; kt < 2; ++kt) {
        bf16x8 bfr = *(const bf16x8*)&h_lds[w * 16 + (l & 15)][kt * 32 + ((l >> 4) << 3)];
        #pragma unroll
        for (int mt = 0; mt < 4; ++mt) {
            bf16x8 afr = wf[(kt * 4 + mt) * 64 + l];
            acc[mt] = __builtin_amdgcn_mfma_f32_16x16x32_bf16(afr, bfr, acc[mt], 0, 0, 0);
        }
    }
    int hrow = rowbase + w * 16 + (l & 15);
    if (hrow < N_NODES) {
        float sc2 = FP8_SCALE * dis[hrow];
        #pragma unroll
        for (int mt = 0; mt < 4; ++mt) {
            int colbase = mt * 16 + ((l >> 4) << 2);
            unsigned d = pack4_fp8(sc2 * acc[mt][0], sc2 * acc[mt][1],
                                   sc2 * acc[mt][2], sc2 * acc[mt][3]);
            if (colbase < 32) tA[(size_t)hrow * 8 + (colbase >> 2)] = d;
            else              tB[(size_t)hrow * 8 + ((colbase - 32) >> 2)] = d;
        }
    }
}

// ---------- last-layer combine: h (bf16) only ----------

__global__ void __launch_bounds__(256) k_combl(const unsigned short* __restrict__ aggA,
                                               const unsigned short* __restrict__ aggB,
                                               const float* __restrict__ dis,
                                               const float* __restrict__ bias,
                                               unsigned short* __restrict__ h) {
    int t = threadIdx.x;
    int row = blockIdx.x * 16 + (t >> 4);
    int sl = t & 15;
    int slh = sl & 7;
    const unsigned short* ag = (sl < 8) ? aggA : aggB;
    ushort4 av = *(const ushort4*)(ag + (size_t)row * 32 + slh * 4);
    float s = dis[row] * FP8_INV;
    ushort4 hv;
    hv.x = f2bf(fmaxf(s * __uint_as_float((unsigned)av.x << 16) + bias[sl * 4 + 0], 0.f));
    hv.y = f2bf(fmaxf(s * __uint_as_float((unsigned)av.y << 16) + bias[sl * 4 + 1], 0.f));
    hv.z = f2bf(fmaxf(s * __uint_as_float((unsigned)av.z << 16) + bias[sl * 4 + 2], 0.f));
    hv.w = f2bf(fmaxf(s * __uint_as_float((unsigned)av.w << 16) + bias[sl * 4 + 3], 0.f));
    *(ushort4*)(h + (size_t)row * 64 + sl * 4) = hv;
}

// ---------- global mean pool: one block per graph, batch sorted ----------

__global__ void __launch_bounds__(256) k_pool(const unsigned short* __restrict__ h,
                                              const int* __restrict__ batch,
                                              float* __restrict__ pooled) {
    __shared__ float part[4][64];
    __shared__ int seg[2];
    int g = blockIdx.x, t = threadIdx.x;
    if (t < 2) {
        int key = g + t;
        int lo = 0, hi = N_NODES;
        while (lo < hi) { int m = (lo + hi) >> 1; if (batch[m] < key) lo = m + 1; else hi = m; }
        seg[t] = lo;
    }
    __syncthreads();
    int start = seg[0], end = seg[1];
    int w = t >> 6, grp = (t >> 4) & 3, sl = t & 15;
    float a[4] = {0.f, 0.f, 0.f, 0.f};
    for (int r = start + w * 4 + grp; r < end; r += 16) {
        ushort4 v = *(const ushort4*)(h + (size_t)r * 64 + sl * 4);
        a[0] += __uint_as_float((unsigned)v.x << 16);
        a[1] += __uint_as_float((unsigned)v.y << 16);
        a[2] += __uint_as_float((unsigned)v.z << 16);
        a[3] += __uint_as_float((unsigned)v.w << 16);
    }
    #pragma unroll
    for (int j = 0; j < 4; ++j) {
        a[j] += __shfl_xor(a[j], 16);
        a[j] += __shfl_xor(a[j], 32);
    }
    if (sl == (t & 63)) {
        #pragma unroll
        for (int j = 0; j < 4; ++j) part[w][sl * 4 + j] = a[j];
    }
    __syncthreads();
    if (t < 64) {
        float s = part[0][t] + part[1][t] + part[2][t] + part[3][t];
        float c = fmaxf((float)(end - start), 1.f);
        pooled[g * 64 + t] = s / c;
    }
}

// ---------- readout MLP + log_softmax ----------

__global__ void k_head(const float* __restrict__ pooled,
                       const float* __restrict__ Wr1, const float* __restrict__ br1,
                       const float* __restrict__ Wr2, const float* __restrict__ br2,
                       const float* __restrict__ Wr3, const float* __restrict__ br3,
                       float* __restrict__ out) {
    int g = blockIdx.x, t = threadIdx.x;  // 64 threads
    __shared__ float p[64], r1[32], r2[16], lg[10];
    p[t] = pooled[g * 64 + t];
    __syncthreads();
    if (t < 32) {
        float a = br1[t];
        for (int k = 0; k < 64; ++k) a += p[k] * Wr1[k * 32 + t];
        r1[t] = fmaxf(a, 0.f);
    }
    __syncthreads();
    if (t < 16) {
        float a = br2[t];
        for (int k = 0; k < 32; ++k) a += r1[k] * Wr2[k * 16 + t];
        r2[t] = fmaxf(a, 0.f);
    }
    __syncthreads();
    if (t < 10) {
        float a = br3[t];
        for (int k = 0; k < 16; ++k) a += r2[k] * Wr3[k * 10 + t];
        lg[t] = a;
    }
    __syncthreads();
    if (t < 10) {
        float m = -1e30f;
        for (int j = 0; j < 10; ++j) m = fmaxf(m, lg[j]);
        float s = 0.f;
        for (int j = 0; j < 10; ++j) s += expf(lg[j] - m);
        out[g * 10 + t] = lg[t] - m - logf(s);
    }
}

extern "C" void kernel_launch(void* const* d_in, const int* in_sizes, int n_in,
                              void* d_out, int out_size, void* d_ws, size_t ws_size,
                              hipStream_t stream) {
    const float* x     = (const float*)d_in[0];
    const int*   ei    = (const int*)d_in[1];
    const int*   batch = (const int*)d_in[2];
    const float* W_emb = (const float*)d_in[4];
    const float* b_emb = (const float*)d_in[5];
    const float* W1    = (const float*)d_in[6];
    const float* b1    = (const float*)d_in[7];
    const float* W2    = (const float*)d_in[8];
    const float* b2    = (const float*)d_in[9];
    const float* W3    = (const float*)d_in[10];
    const float* b3    = (const float*)d_in[11];
    const float* W4    = (const float*)d_in[12];
    const float* b4    = (const float*)d_in[13];
    const float* Wr1   = (const float*)d_in[14];
    const float* br1   = (const float*)d_in[15];
    const float* Wr2   = (const float*)d_in[16];
    const float* br2   = (const float*)d_in[17];
    const float* Wr3   = (const float*)d_in[18];
    const float* br3   = (const float*)d_in[19];
    float* out = (float*)d_out;

    char* ws = (char*)d_ws;
    size_t off = 0;
    auto alloc = [&](size_t b) { char* p = ws + off; off += (b + 511) & ~(size_t)511; return p; };
    size_t TBYTES = (size_t)(N_NODES + 1) * 32;
    int*   col    = (int*)  alloc((size_t)NBKT * CAP * 4);     // 18.4 MB
    char*  ebufh  =         alloc((size_t)NBKT * CAP * 4);     // ebuf, later reused as h
    unsigned char* T0a = (unsigned char*)alloc(TBYTES);        // fp8 half-tables (+dummy row)
    unsigned char* T0b = (unsigned char*)alloc(TBYTES);
    unsigned char* T1a = (unsigned char*)alloc(TBYTES);
    unsigned char* T1b = (unsigned char*)alloc(TBYTES);
    unsigned short* aggA = (unsigned short*)alloc((size_t)N_NODES * 32 * 2);  // bf16
    unsigned short* aggB = (unsigned short*)alloc((size_t)N_NODES * 32 * 2);
    int2*  rc     = (int2*) alloc((size_t)N_NODES * 8);
    float* dis    = (float*)alloc((size_t)N_NODES * 4);
    int*   gcur   = (int*)  alloc((size_t)NBKT * 4);
    float* Wc     = (float*)alloc(32 * 64 * 4);
    float* bc     = (float*)alloc(64 * 4);
    unsigned short* Wfrag = (unsigned short*)alloc(3 * 4096 * 2);
    float* pooled = (float*)alloc((size_t)N_GRAPHS * 64 * 4);

    int* ebuf = (int*)ebufh;
    unsigned short* hbuf = (unsigned short*)ebufh;   // alias: h lives where ebuf was

    hipMemsetAsync(T0a + (size_t)N_NODES * 32, 0, 32, stream);
    hipMemsetAsync(T0b + (size_t)N_NODES * 32, 0, 32, stream);
    hipMemsetAsync(T1a + (size_t)N_NODES * 32, 0, 32, stream);
    hipMemsetAsync(T1b + (size_t)N_NODES * 32, 0, 32, stream);

    k_ginit<<<(NBKT + 255) / 256, 256, 0, stream>>>(gcur);
    k_bucket<<<NBLK_A, 256, 0, stream>>>(ei, gcur, ebuf);
    k_fill2<<<NBKT, 256, 0, stream>>>(ebuf, gcur, rc, dis, col);
    k_wc<<<1, 256, 0, stream>>>(W_emb, b_emb, W1, Wc, bc);
    k_wprep<<<3, 256, 0, stream>>>(W2, W3, W4, Wfrag);

    int nbm = N_NODES / 16;        // 6250
    int nba = N_NODES / 32;        // 3125
    int nbc = (N_NODES + 63) / 64; // 1563

    k_mm1<<<nbm, 256, 0, stream>>>(x, Wc, bc, dis, T0a, T0b);

    const float* lb[4] = {b1, b2, b3, b4};
    unsigned char* cura = T0a; unsigned char* curb = T0b;
    unsigned char* nxta = T1a; unsigned char* nxtb = T1b;
    for (int l = 0; l < 4; ++l) {
        k_agg<<<nba, 256, 0, stream>>>((const unsigned*)cura, rc, col, aggA);
        k_agg<<<nba, 256, 0, stream>>>((const unsigned*)curb, rc, col, aggB);
        if (l < 3) {
            k_combm<<<nbc, 256, 0, stream>>>(aggA, aggB, dis, lb[l], Wfrag + (size_t)l * 4096,
                                             (unsigned*)nxta, (unsigned*)nxtb);
            unsigned char* ta = cura; cura = nxta; nxta = ta;
            unsigned char* tb = curb; curb = nxtb; nxtb = tb;
        } else {
            k_combl<<<nbm, 256, 0, stream>>>(aggA, aggB, dis, lb[l], hbuf);
        }
    }

    k_pool<<<N_GRAPHS, 256, 0, stream>>>(hbuf, batch, pooled);
    k_head<<<N_GRAPHS, 64, 0, stream>>>(pooled, Wr1, br1, Wr2, br2, Wr3, br3, out);
}

// Round 11
// 329.482 us; speedup vs baseline: 1.6304x; 1.0317x over previous
//
#include <hip/hip_runtime.h>
#include <hip/hip_bf16.h>

typedef __hip_bfloat16 bf16;
typedef short bf16x8 __attribute__((ext_vector_type(8)));
typedef float f32x4 __attribute__((ext_vector_type(4)));

#define N_NODES 100000
#define N_EDGES 3200000
#define N_GRAPHS 512
#define NBKT    ((N_NODES + 255) / 256)               // 391 buckets of 256 nodes
#define CAP     11776                                 // slots per bucket window (16-aligned)
#define EPB     8192                                  // edges per k_bucket block
#define NBLK_A  ((N_EDGES + EPB - 1) / EPB)           // 391
#define FP8_SCALE 64.0f
#define FP8_INV   (1.0f / 64.0f)

// ---------- fp8 e4m3 helpers (OCP on gfx950) ----------

__device__ inline unsigned char f32_to_fp8(float v) {
#if __has_builtin(__builtin_amdgcn_cvt_pk_fp8_f32)
    return (unsigned char)(__builtin_amdgcn_cvt_pk_fp8_f32(v, v, 0, 0) & 0xFF);
#else
    unsigned u = __float_as_uint(v);
    unsigned s = (u >> 24) & 0x80;
    float a = fabsf(v);
    if (a < 9.765625e-4f) return (unsigned char)s;
    if (a >= 448.f) return (unsigned char)(s | 0x7E);
    if (a < 0.015625f) {
        int mm = (int)(a * 512.f + 0.5f);
        if (mm > 7) mm = 7;
        return (unsigned char)(s | mm);
    }
    unsigned keep = (u >> 20) & 1;
    u = (u & 0x7FFFFFFF) + 0x7FFFF + keep;
    unsigned e = ((u >> 23) & 0xFF) - 120;
    if (e > 15) { e = 15; return (unsigned char)(s | 0x7E); }
    return (unsigned char)(s | (e << 3) | ((u >> 20) & 7));
#endif
}

__device__ inline unsigned pack4_fp8(float o0, float o1, float o2, float o3) {
#if __has_builtin(__builtin_amdgcn_cvt_pk_fp8_f32)
    unsigned d = 0;
    d = (unsigned)__builtin_amdgcn_cvt_pk_fp8_f32(o0, o1, (int)d, 0);
    d = (unsigned)__builtin_amdgcn_cvt_pk_fp8_f32(o2, o3, (int)d, 1);
    return d;
#else
    return (unsigned)f32_to_fp8(o0) | ((unsigned)f32_to_fp8(o1) << 8) |
           ((unsigned)f32_to_fp8(o2) << 16) | ((unsigned)f32_to_fp8(o3) << 24);
#endif
}

__device__ inline float fp8_to_f32(unsigned int b) {
    unsigned s = (b >> 7) & 1, e = (b >> 3) & 15, m = b & 7;
    float v = (e == 0) ? (float)m * 0.001953125f
                       : __uint_as_float(((e + 120u) << 23) | (m << 20));
    return s ? -v : v;
}

__device__ inline void acc4(float* a, unsigned v) {
#if __has_builtin(__builtin_amdgcn_cvt_pk_f32_fp8)
    typedef float f32x2 __attribute__((ext_vector_type(2)));
    f32x2 lo = __builtin_amdgcn_cvt_pk_f32_fp8((int)v, false);
    f32x2 hi = __builtin_amdgcn_cvt_pk_f32_fp8((int)v, true);
    a[0] += lo.x; a[1] += lo.y; a[2] += hi.x; a[3] += hi.y;
#elif __has_builtin(__builtin_amdgcn_cvt_f32_fp8)
    a[0] += __builtin_amdgcn_cvt_f32_fp8(v, 0);
    a[1] += __builtin_amdgcn_cvt_f32_fp8(v, 1);
    a[2] += __builtin_amdgcn_cvt_f32_fp8(v, 2);
    a[3] += __builtin_amdgcn_cvt_f32_fp8(v, 3);
#else
    a[0] += fp8_to_f32(v & 0xFF);
    a[1] += fp8_to_f32((v >> 8) & 0xFF);
    a[2] += fp8_to_f32((v >> 16) & 0xFF);
    a[3] += fp8_to_f32((v >> 24) & 0xFF);
#endif
}

__device__ inline unsigned short f2bf(float x) {
    unsigned u = __float_as_uint(x);
    return (unsigned short)((u + 0x7FFF + ((u >> 16) & 1)) >> 16);
}

// ---------- init: per-bucket cursors + zero dummy gather rows ----------

__global__ void k_ginit(int* __restrict__ gcur, unsigned* __restrict__ t0a,
                        unsigned* __restrict__ t0b, unsigned* __restrict__ t1a,
                        unsigned* __restrict__ t1b) {
    int b = blockIdx.x * blockDim.x + threadIdx.x;
    if (b < NBKT) gcur[b] = b * CAP;
    if (blockIdx.x == 0 && threadIdx.x < 8) {
        size_t o = (size_t)N_NODES * 8 + threadIdx.x;
        t0a[o] = 0; t0b[o] = 0; t1a[o] = 0; t1b[o] = 0;
    }
}

// ---------- Pass A: bin edges by dst>>8 into fixed-CAP bucket windows ----------

__global__ void __launch_bounds__(512) k_bucket(const int* __restrict__ ei,
                                                int* __restrict__ gcur,
                                                int* __restrict__ ebuf) {
    __shared__ int cnt[NBKT];
    __shared__ int base[NBKT];
    int t = threadIdx.x;
    for (int i = t; i < NBKT; i += 512) cnt[i] = 0;
    __syncthreads();
    int e0 = blockIdx.x * EPB + t;
    int sv[16], dv[16];
    #pragma unroll
    for (int j = 0; j < 16; ++j) {
        int e = e0 + j * 512;
        if (e < N_EDGES) {
            sv[j] = ei[e];
            dv[j] = ei[N_EDGES + e];
            atomicAdd(&cnt[dv[j] >> 8], 1);
        } else dv[j] = -1;
    }
    __syncthreads();
    for (int i = t; i < NBKT; i += 512) {
        base[i] = atomicAdd(&gcur[i], cnt[i]);
        cnt[i] = 0;
    }
    __syncthreads();
    #pragma unroll
    for (int j = 0; j < 16; ++j) {
        if (dv[j] >= 0) {
            int b = dv[j] >> 8;
            int r = atomicAdd(&cnt[b], 1);
            ebuf[base[b] + r] = (sv[j] << 8) | (dv[j] & 255);
        }
    }
}

// ---------- Pass B: per-bucket histogram -> rc/dis, 16-aligned col, pad-gap dummies ----------

__global__ void __launch_bounds__(256) k_fill2(const int* __restrict__ ebuf,
                                               const int* __restrict__ gcur,
                                               int2* __restrict__ rc,
                                               float* __restrict__ dis,
                                               int* __restrict__ col) {
    __shared__ int cnt[256];
    __shared__ int sc[256];
    __shared__ int exs[256];
    __shared__ int cur[256];
    int b = blockIdx.x, t = threadIdx.x;
    int n0 = b * 256;
    int nrec = gcur[b] - b * CAP;
    const int* eb = ebuf + (size_t)b * CAP;
    int* cw = col + (size_t)b * CAP;
    cnt[t] = 0; cur[t] = 0;
    __syncthreads();
    for (int i = t; i < nrec; i += 256)
        atomicAdd(&cnt[eb[i] & 255], 1);
    __syncthreads();
    int c0 = cnt[t];
    int a16 = (c0 + 15) & ~15;
    sc[t] = a16; __syncthreads();
    for (int off = 1; off < 256; off <<= 1) {
        int u = (t >= off) ? sc[t - off] : 0;
        __syncthreads();
        sc[t] += u;
        __syncthreads();
    }
    int myex = sc[t] - a16;
    exs[t] = myex;
    int n = n0 + t;
    if (n < N_NODES) {
        rc[n] = make_int2(b * CAP + myex, c0);
        dis[n] = rsqrtf((float)(c0 + 1));
    }
    // fill only the 16-align padding gap of this thread's node with dummies
    for (int i = myex + c0; i < myex + a16; ++i) cw[i] = N_NODES;
    __syncthreads();
    for (int i = t; i < nrec; i += 256) {
        int rec = eb[i];
        int dl = rec & 255;
        cw[exs[dl] + atomicAdd(&cur[dl], 1)] = rec >> 8;
    }
}

// ---------- folded embedding weight: Wc = W_emb@W1, bc = b_emb@W1 ----------

__global__ void k_wc(const float* __restrict__ W_emb, const float* __restrict__ b_emb,
                     const float* __restrict__ W1, float* __restrict__ Wc,
                     float* __restrict__ bc) {
    int t = threadIdx.x;
    for (int i = t; i < 32 * 64; i += 256) {
        int a = i / 64, b = i % 64;
        float acc = 0.f;
        for (int k = 0; k < 64; ++k) acc += W_emb[a * 64 + k] * W1[k * 64 + b];
        Wc[i] = acc;
    }
    if (t < 64) {
        float acc = 0.f;
        for (int k = 0; k < 64; ++k) acc += b_emb[k] * W1[k * 64 + t];
        bc[t] = acc;
    }
}

// ---------- Wn -> per-lane MFMA A-fragment layout (A = Wn^T), bf16 ----------

__global__ void k_wprep(const float* __restrict__ W2, const float* __restrict__ W3,
                        const float* __restrict__ W4, unsigned short* __restrict__ Wfrag) {
    const float* W = (blockIdx.x == 0) ? W2 : (blockIdx.x == 1) ? W3 : W4;
    unsigned short* dst = Wfrag + (size_t)blockIdx.x * 4096;
    int t = threadIdx.x;
    for (int i = 0; i < 16; ++i) {
        int flat = t * 16 + i;
        int j = flat & 7, lane = (flat >> 3) & 63, mt = (flat >> 9) & 3, kt = flat >> 11;
        int m = mt * 16 + (lane & 15);
        int k = kt * 32 + ((lane >> 4) << 3) + j;
        dst[flat] = f2bf(W[k * 64 + m]);
    }
}

// ---------- layer-1 matmul -> split fp8 half-tables ----------

__global__ void __launch_bounds__(256) k_mm1(const float* __restrict__ inp,
                                             const float* __restrict__ W,
                                             const float* __restrict__ bias,
                                             const float* __restrict__ dis,
                                             unsigned char* __restrict__ tA,
                                             unsigned char* __restrict__ tB) {
    __shared__ float Wl[32][64];
    __shared__ float hs[16][32];
    int t = threadIdx.x;
    for (int i = t; i < 32 * 64; i += 256) Wl[i / 64][i % 64] = W[i];
    int row0 = blockIdx.x * 16;
    for (int i = t; i < 16 * 32; i += 256) {
        int r = row0 + i / 32, k = i % 32;
        hs[i / 32][k] = inp[(size_t)r * 32 + k];
    }
    __syncthreads();
    int c = t & 63, rg = t >> 6;
    float a0 = 0, a1 = 0, a2 = 0, a3 = 0;
    #pragma unroll 4
    for (int k = 0; k < 32; ++k) {
        float wv = Wl[k][c];
        a0 += hs[rg * 4 + 0][k] * wv;
        a1 += hs[rg * 4 + 1][k] * wv;
        a2 += hs[rg * 4 + 2][k] * wv;
        a3 += hs[rg * 4 + 3][k] * wv;
    }
    float bv = bias[c];
    int r = row0 + rg * 4;
    unsigned char* dst = (c < 32) ? tA : tB;
    int cc = c & 31;
    dst[(size_t)(r + 0) * 32 + cc] = f32_to_fp8(FP8_SCALE * dis[r + 0] * (a0 + bv));
    dst[(size_t)(r + 1) * 32 + cc] = f32_to_fp8(FP8_SCALE * dis[r + 1] * (a1 + bv));
    dst[(size_t)(r + 2) * 32 + cc] = f32_to_fp8(FP8_SCALE * dis[r + 2] * (a2 + bv));
    dst[(size_t)(r + 3) * 32 + cc] = f32_to_fp8(FP8_SCALE * dis[r + 3] * (a3 + bv));
}

// ---------- AGG v5: 8 rows/wave x 8 feature-dwords, software-pipelined gathers
//            (gathers for it+1 in flight while acc of it runs) ----------
// agg[row, 32 feats] = tph[row] + sum_e tph[col[e]]   (bf16 out)

__global__ void __launch_bounds__(256, 4) k_agg(const unsigned* __restrict__ tph,
                                                const int2* __restrict__ rc,
                                                const int* __restrict__ col,
                                                unsigned short* __restrict__ agg) {
    int row = blockIdx.x * 32 + (threadIdx.x >> 3);
    int sl = threadIdx.x & 7;
    float a[4] = {0.f, 0.f, 0.f, 0.f};
    float b[4] = {0.f, 0.f, 0.f, 0.f};
    acc4(a, tph[(size_t)row * 8 + sl]);                // self-loop term
    int2 r = rc[row];
    int nit = (r.y + 15) >> 4;                         // 16-edge iterations
    const int* cp = col + r.x;
    if (nit > 0) {
        unsigned g[16];
        #pragma unroll
        for (int u = 0; u < 16; ++u) g[u] = tph[(size_t)cp[u] * 8 + sl];
        for (int it = 1; it < nit; ++it) {
            const int* np = cp + it * 16;
            unsigned h[16];
            #pragma unroll
            for (int u = 0; u < 16; ++u) h[u] = tph[(size_t)np[u] * 8 + sl];  // in flight
            #pragma unroll
            for (int u = 0; u < 16; u += 2) { acc4(a, g[u]); acc4(b, g[u + 1]); }
            #pragma unroll
            for (int u = 0; u < 16; ++u) g[u] = h[u];
        }
        #pragma unroll
        for (int u = 0; u < 16; u += 2) { acc4(a, g[u]); acc4(b, g[u + 1]); }
    }
    ushort4 o;
    o.x = f2bf(a[0] + b[0]); o.y = f2bf(a[1] + b[1]);
    o.z = f2bf(a[2] + b[2]); o.w = f2bf(a[3] + b[3]);
    *(ushort4*)(agg + (size_t)row * 32 + sl * 4) = o;
}

// ---------- MFMA COMBINE: h = relu(dis/S*agg + b); next halves = fp8(S*dis*(h@Wn)) ----------

__global__ void __launch_bounds__(256) k_combm(const unsigned short* __restrict__ aggA,
                                               const unsigned short* __restrict__ aggB,
                                               const float* __restrict__ dis,
                                               const float* __restrict__ bias,
                                               const unsigned short* __restrict__ Wfrag,
                                               unsigned* __restrict__ tA,
                                               unsigned* __restrict__ tB) {
    __shared__ unsigned short h_lds[64][72];          // bf16, padded stride
    int t = threadIdx.x;
    int rowbase = blockIdx.x * 64;
    {
        int row = t >> 2, q = t & 3;
        int grow = rowbase + row;
        if (grow < N_NODES) {
            float f = dis[grow] * FP8_INV;
            #pragma unroll
            for (int i = 0; i < 4; ++i) {
                int c0 = q * 16 + i * 4;
                const unsigned short* src = ((c0 < 32) ? aggA : aggB) +
                                            (size_t)grow * 32 + (c0 & 31);
                ushort4 v = *(const ushort4*)src;
                short4 o;
                o.x = (short)f2bf(fmaxf(f * __uint_as_float((unsigned)v.x << 16) + bias[c0 + 0], 0.f));
                o.y = (short)f2bf(fmaxf(f * __uint_as_float((unsigned)v.y << 16) + bias[c0 + 1], 0.f));
                o.z = (short)f2bf(fmaxf(f * __uint_as_float((unsigned)v.z << 16) + bias[c0 + 2], 0.f));
                o.w = (short)f2bf(fmaxf(f * __uint_as_float((unsigned)v.w << 16) + bias[c0 + 3], 0.f));
                *(short4*)&h_lds[row][c0] = o;
            }
        } else {
            #pragma unroll
            for (int i = 0; i < 4; ++i)
                *(short4*)&h_lds[row][q * 16 + i * 4] = make_short4(0, 0, 0, 0);
        }
    }
    __syncthreads();
    int w = t >> 6, l = t & 63;
    f32x4 acc[4] = {{0,0,0,0}, {0,0,0,0}, {0,0,0,0}, {0,0,0,0}};
    const bf16x8* wf = (const bf16x8*)Wfrag;
    #pragma unroll
    for (int kt = 0; kt < 2; ++kt) {
        bf16x8 bfr = *(const bf16x8*)&h_lds[w * 16 + (l & 15)][kt * 32 + ((l >> 4) << 3)];
        #pragma unroll
        for (int mt = 0; mt < 4; ++mt) {
            bf16x8 afr = wf[(kt * 4 + mt) * 64 + l];
            acc[mt] = __builtin_amdgcn_mfma_f32_16x16x32_bf16(afr, bfr, acc[mt], 0, 0, 0);
        }
    }
    int hrow = rowbase + w * 16 + (l & 15);
    if (hrow < N_NODES) {
        float sc2 = FP8_SCALE * dis[hrow];
        #pragma unroll
        for (int mt = 0; mt < 4; ++mt) {
            int colbase = mt * 16 + ((l >> 4) << 2);
            unsigned d = pack4_fp8(sc2 * acc[mt][0], sc2 * acc[mt][1],
                                   sc2 * acc[mt][2], sc2 * acc[mt][3]);
            if (colbase < 32) tA[(size_t)hrow * 8 + (colbase >> 2)] = d;
            else              tB[(size_t)hrow * 8 + ((colbase - 32) >> 2)] = d;
        }
    }
}

// ---------- last-layer combine: h (bf16) only ----------

__global__ void __launch_bounds__(256) k_combl(const unsigned short* __restrict__ aggA,
                                               const unsigned short* __restrict__ aggB,
                                               const float* __restrict__ dis,
                                               const float* __restrict__ bias,
                                               unsigned short* __restrict__ h) {
    int t = threadIdx.x;
    int row = blockIdx.x * 16 + (t >> 4);
    int sl = t & 15;
    int slh = sl & 7;
    const unsigned short* ag = (sl < 8) ? aggA : aggB;
    ushort4 av = *(const ushort4*)(ag + (size_t)row * 32 + slh * 4);
    float s = dis[row] * FP8_INV;
    ushort4 hv;
    hv.x = f2bf(fmaxf(s * __uint_as_float((unsigned)av.x << 16) + bias[sl * 4 + 0], 0.f));
    hv.y = f2bf(fmaxf(s * __uint_as_float((unsigned)av.y << 16) + bias[sl * 4 + 1], 0.f));
    hv.z = f2bf(fmaxf(s * __uint_as_float((unsigned)av.z << 16) + bias[sl * 4 + 2], 0.f));
    hv.w = f2bf(fmaxf(s * __uint_as_float((unsigned)av.w << 16) + bias[sl * 4 + 3], 0.f));
    *(ushort4*)(h + (size_t)row * 64 + sl * 4) = hv;
}

// ---------- global mean pool: one block per graph, batch sorted ----------

__global__ void __launch_bounds__(256) k_pool(const unsigned short* __restrict__ h,
                                              const int* __restrict__ batch,
                                              float* __restrict__ pooled) {
    __shared__ float part[4][64];
    __shared__ int seg[2];
    int g = blockIdx.x, t = threadIdx.x;
    if (t < 2) {
        int key = g + t;
        int lo = 0, hi = N_NODES;
        while (lo < hi) { int m = (lo + hi) >> 1; if (batch[m] < key) lo = m + 1; else hi = m; }
        seg[t] = lo;
    }
    __syncthreads();
    int start = seg[0], end = seg[1];
    int w = t >> 6, grp = (t >> 4) & 3, sl = t & 15;
    float a[4] = {0.f, 0.f, 0.f, 0.f};
    for (int r = start + w * 4 + grp; r < end; r += 16) {
        ushort4 v = *(const ushort4*)(h + (size_t)r * 64 + sl * 4);
        a[0] += __uint_as_float((unsigned)v.x << 16);
        a[1] += __uint_as_float((unsigned)v.y << 16);
        a[2] += __uint_as_float((unsigned)v.z << 16);
        a[3] += __uint_as_float((unsigned)v.w << 16);
    }
    #pragma unroll
    for (int j = 0; j < 4; ++j) {
        a[j] += __shfl_xor(a[j], 16);
        a[j] += __shfl_xor(a[j], 32);
    }
    if (sl == (t & 63)) {
        #pragma unroll
        for (int j = 0; j < 4; ++j) part[w][sl * 4 + j] = a[j];
    }
    __syncthreads();
    if (t < 64) {
        float s = part[0][t] + part[1][t] + part[2][t] + part[3][t];
        float c = fmaxf((float)(end - start), 1.f);
        pooled[g * 64 + t] = s / c;
    }
}

// ---------- readout MLP + log_softmax ----------

__global__ void k_head(const float* __restrict__ pooled,
                       const float* __restrict__ Wr1, const float* __restrict__ br1,
                       const float* __restrict__ Wr2, const float* __restrict__ br2,
                       const float* __restrict__ Wr3, const float* __restrict__ br3,
                       float* __restrict__ out) {
    int g = blockIdx.x, t = threadIdx.x;  // 64 threads
    __shared__ float p[64], r1[32], r2[16], lg[10];
    p[t] = pooled[g * 64 + t];
    __syncthreads();
    if (t < 32) {
        float a = br1[t];
        for (int k = 0; k < 64; ++k) a += p[k] * Wr1[k * 32 + t];
        r1[t] = fmaxf(a, 0.f);
    }
    __syncthreads();
    if (t < 16) {
        float a = br2[t];
        for (int k = 0; k < 32; ++k) a += r1[k] * Wr2[k * 16 + t];
        r2[t] = fmaxf(a, 0.f);
    }
    __syncthreads();
    if (t < 10) {
        float a = br3[t];
        for (int k = 0; k < 16; ++k) a += r2[k] * Wr3[k * 10 + t];
        lg[t] = a;
    }
    __syncthreads();
    if (t < 10) {
        float m = -1e30f;
        for (int j = 0; j < 10; ++j) m = fmaxf(m, lg[j]);
        float s = 0.f;
        for (int j = 0; j < 10; ++j) s += expf(lg[j] - m);
        out[g * 10 + t] = lg[t] - m - logf(s);
    }
}

extern "C" void kernel_launch(void* const* d_in, const int* in_sizes, int n_in,
                              void* d_out, int out_size, void* d_ws, size_t ws_size,
                              hipStream_t stream) {
    const float* x     = (const float*)d_in[0];
    const int*   ei    = (const int*)d_in[1];
    const int*   batch = (const int*)d_in[2];
    const float* W_emb = (const float*)d_in[4];
    const float* b_emb = (const float*)d_in[5];
    const float* W1    = (const float*)d_in[6];
    const float* b1    = (const float*)d_in[7];
    const float* W2    = (const float*)d_in[8];
    const float* b2    = (const float*)d_in[9];
    const float* W3    = (const float*)d_in[10];
    const float* b3    = (const float*)d_in[11];
    const float* W4    = (const float*)d_in[12];
    const float* b4    = (const float*)d_in[13];
    const float* Wr1   = (const float*)d_in[14];
    const float* br1   = (const float*)d_in[15];
    const float* Wr2   = (const float*)d_in[16];
    const float* br2   = (const float*)d_in[17];
    const float* Wr3   = (const float*)d_in[18];
    const float* br3   = (const float*)d_in[19];
    float* out = (float*)d_out;

    char* ws = (char*)d_ws;
    size_t off = 0;
    auto alloc = [&](size_t b) { char* p = ws + off; off += (b + 511) & ~(size_t)511; return p; };
    size_t TBYTES = (size_t)(N_NODES + 1) * 32;
    int*   col    = (int*)  alloc((size_t)NBKT * CAP * 4);     // 18.4 MB
    char*  ebufh  =         alloc((size_t)NBKT * CAP * 4);     // ebuf, later reused as h
    unsigned char* T0a = (unsigned char*)alloc(TBYTES);        // fp8 half-tables (+dummy row)
    unsigned char* T0b = (unsigned char*)alloc(TBYTES);
    unsigned char* T1a = (unsigned char*)alloc(TBYTES);
    unsigned char* T1b = (unsigned char*)alloc(TBYTES);
    unsigned short* aggA = (unsigned short*)alloc((size_t)N_NODES * 32 * 2);  // bf16
    unsigned short* aggB = (unsigned short*)alloc((size_t)N_NODES * 32 * 2);
    int2*  rc     = (int2*) alloc((size_t)N_NODES * 8);
    float* dis    = (float*)alloc((size_t)N_NODES * 4);
    int*   gcur   = (int*)  alloc((size_t)NBKT * 4);
    float* Wc     = (float*)alloc(32 * 64 * 4);
    float* bc     = (float*)alloc(64 * 4);
    unsigned short* Wfrag = (unsigned short*)alloc(3 * 4096 * 2);
    float* pooled = (float*)alloc((size_t)N_GRAPHS * 64 * 4);

    int* ebuf = (int*)ebufh;
    unsigned short* hbuf = (unsigned short*)ebufh;   // alias: h lives where ebuf was

    k_ginit<<<(NBKT + 255) / 256, 256, 0, stream>>>(gcur, (unsigned*)T0a, (unsigned*)T0b,
                                                    (unsigned*)T1a, (unsigned*)T1b);
    k_bucket<<<NBLK_A, 512, 0, stream>>>(ei, gcur, ebuf);
    k_fill2<<<NBKT, 256, 0, stream>>>(ebuf, gcur, rc, dis, col);
    k_wc<<<1, 256, 0, stream>>>(W_emb, b_emb, W1, Wc, bc);
    k_wprep<<<3, 256, 0, stream>>>(W2, W3, W4, Wfrag);

    int nbm = N_NODES / 16;        // 6250
    int nba = N_NODES / 32;        // 3125
    int nbc = (N_NODES + 63) / 64; // 1563

    k_mm1<<<nbm, 256, 0, stream>>>(x, Wc, bc, dis, T0a, T0b);

    const float* lb[4] = {b1, b2, b3, b4};
    unsigned char* cura = T0a; unsigned char* curb = T0b;
    unsigned char* nxta = T1a; unsigned char* nxtb = T1b;
    for (int l = 0; l < 4; ++l) {
        k_agg<<<nba, 256, 0, stream>>>((const unsigned*)cura, rc, col, aggA);
        k_agg<<<nba, 256, 0, stream>>>((const unsigned*)curb, rc, col, aggB);
        if (l < 3) {
            k_combm<<<nbc, 256, 0, stream>>>(aggA, aggB, dis, lb[l], Wfrag + (size_t)l * 4096,
                                             (unsigned*)nxta, (unsigned*)nxtb);
            unsigned char* ta = cura; cura = nxta; nxta = ta;
            unsigned char* tb = curb; curb = nxtb; nxtb = tb;
        } else {
            k_combl<<<nbm, 256, 0, stream>>>(aggA, aggB, dis, lb[l], hbuf);
        }
    }

    k_pool<<<N_GRAPHS, 256, 0, stream>>>(hbuf, batch, pooled);
    k_head<<<N_GRAPHS, 64, 0, stream>>>(pooled, Wr1, br1, Wr2, br2, Wr3, br3, out);
}

// Round 12
// 321.636 us; speedup vs baseline: 1.6702x; 1.0244x over previous
//
#include <hip/hip_runtime.h>
#include <hip/hip_bf16.h>

typedef __hip_bfloat16 bf16;
typedef short bf16x8 __attribute__((ext_vector_type(8)));
typedef float f32x4 __attribute__((ext_vector_type(4)));

#define N_NODES 100000
#define N_EDGES 3200000
#define N_GRAPHS 512
#define NBKT    ((N_NODES + 255) / 256)               // 391 buckets of 256 nodes
#define CAP     10496                                 // slots per bucket window (8-aligned)
#define EPB     16384                                 // edges per k_bucket block
#define NBLK_A  ((N_EDGES + EPB - 1) / EPB)           // 196
#define FP8_SCALE 64.0f
#define FP8_INV   (1.0f / 64.0f)

// ---------- fp8 e4m3 helpers (OCP on gfx950) ----------

__device__ inline unsigned char f32_to_fp8(float v) {
#if __has_builtin(__builtin_amdgcn_cvt_pk_fp8_f32)
    return (unsigned char)(__builtin_amdgcn_cvt_pk_fp8_f32(v, v, 0, 0) & 0xFF);
#else
    unsigned u = __float_as_uint(v);
    unsigned s = (u >> 24) & 0x80;
    float a = fabsf(v);
    if (a < 9.765625e-4f) return (unsigned char)s;
    if (a >= 448.f) return (unsigned char)(s | 0x7E);
    if (a < 0.015625f) {
        int mm = (int)(a * 512.f + 0.5f);
        if (mm > 7) mm = 7;
        return (unsigned char)(s | mm);
    }
    unsigned keep = (u >> 20) & 1;
    u = (u & 0x7FFFFFFF) + 0x7FFFF + keep;
    unsigned e = ((u >> 23) & 0xFF) - 120;
    if (e > 15) { e = 15; return (unsigned char)(s | 0x7E); }
    return (unsigned char)(s | (e << 3) | ((u >> 20) & 7));
#endif
}

__device__ inline unsigned pack4_fp8(float o0, float o1, float o2, float o3) {
#if __has_builtin(__builtin_amdgcn_cvt_pk_fp8_f32)
    unsigned d = 0;
    d = (unsigned)__builtin_amdgcn_cvt_pk_fp8_f32(o0, o1, (int)d, 0);
    d = (unsigned)__builtin_amdgcn_cvt_pk_fp8_f32(o2, o3, (int)d, 1);
    return d;
#else
    return (unsigned)f32_to_fp8(o0) | ((unsigned)f32_to_fp8(o1) << 8) |
           ((unsigned)f32_to_fp8(o2) << 16) | ((unsigned)f32_to_fp8(o3) << 24);
#endif
}

__device__ inline float fp8_to_f32(unsigned int b) {
    unsigned s = (b >> 7) & 1, e = (b >> 3) & 15, m = b & 7;
    float v = (e == 0) ? (float)m * 0.001953125f
                       : __uint_as_float(((e + 120u) << 23) | (m << 20));
    return s ? -v : v;
}

__device__ inline void acc4(float* a, unsigned v) {
#if __has_builtin(__builtin_amdgcn_cvt_pk_f32_fp8)
    typedef float f32x2 __attribute__((ext_vector_type(2)));
    f32x2 lo = __builtin_amdgcn_cvt_pk_f32_fp8((int)v, false);
    f32x2 hi = __builtin_amdgcn_cvt_pk_f32_fp8((int)v, true);
    a[0] += lo.x; a[1] += lo.y; a[2] += hi.x; a[3] += hi.y;
#elif __has_builtin(__builtin_amdgcn_cvt_f32_fp8)
    a[0] += __builtin_amdgcn_cvt_f32_fp8(v, 0);
    a[1] += __builtin_amdgcn_cvt_f32_fp8(v, 1);
    a[2] += __builtin_amdgcn_cvt_f32_fp8(v, 2);
    a[3] += __builtin_amdgcn_cvt_f32_fp8(v, 3);
#else
    a[0] += fp8_to_f32(v & 0xFF);
    a[1] += fp8_to_f32((v >> 8) & 0xFF);
    a[2] += fp8_to_f32((v >> 16) & 0xFF);
    a[3] += fp8_to_f32((v >> 24) & 0xFF);
#endif
}

__device__ inline unsigned short f2bf(float x) {
    unsigned u = __float_as_uint(x);
    return (unsigned short)((u + 0x7FFF + ((u >> 16) & 1)) >> 16);
}

// ---------- setup: Wc/bc, Wfrag, gcur, dummy rows — one kernel ----------

__global__ void k_setup(const float* __restrict__ W_emb, const float* __restrict__ b_emb,
                        const float* __restrict__ W1, const float* __restrict__ W2,
                        const float* __restrict__ W3, const float* __restrict__ W4,
                        float* __restrict__ Wc, float* __restrict__ bc,
                        unsigned short* __restrict__ Wfrag, int* __restrict__ gcur,
                        unsigned* __restrict__ t0a, unsigned* __restrict__ t0b,
                        unsigned* __restrict__ t1a, unsigned* __restrict__ t1b) {
    int blk = blockIdx.x, t = threadIdx.x;
    if (blk == 0) {                       // folded embedding: Wc = W_emb@W1, bc = b_emb@W1
        for (int i = t; i < 32 * 64; i += 256) {
            int a = i / 64, b = i % 64;
            float acc = 0.f;
            for (int k = 0; k < 64; ++k) acc += W_emb[a * 64 + k] * W1[k * 64 + b];
            Wc[i] = acc;
        }
        if (t < 64) {
            float acc = 0.f;
            for (int k = 0; k < 64; ++k) acc += b_emb[k] * W1[k * 64 + t];
            bc[t] = acc;
        }
    } else if (blk <= 3) {                // MFMA A-fragments of Wn^T
        const float* W = (blk == 1) ? W2 : (blk == 2) ? W3 : W4;
        unsigned short* dst = Wfrag + (size_t)(blk - 1) * 4096;
        for (int i = 0; i < 16; ++i) {
            int flat = t * 16 + i;
            int j = flat & 7, lane = (flat >> 3) & 63, mt = (flat >> 9) & 3, kt = flat >> 11;
            int m = mt * 16 + (lane & 15);
            int k = kt * 32 + ((lane >> 4) << 3) + j;
            dst[flat] = f2bf(W[k * 64 + m]);
        }
    } else {                              // gcur init + dummy gather rows
        for (int b = t; b < NBKT; b += 256) gcur[b] = b * CAP;
        if (t < 8) {
            size_t o = (size_t)N_NODES * 8 + t;
            t0a[o] = 0; t0b[o] = 0; t1a[o] = 0; t1b[o] = 0;
        }
    }
}

// ---------- Pass A: bin edges by dst>>8 into fixed-CAP bucket windows ----------

__global__ void __launch_bounds__(512) k_bucket(const int* __restrict__ ei,
                                                int* __restrict__ gcur,
                                                int* __restrict__ ebuf) {
    __shared__ int cnt[NBKT];
    __shared__ int base[NBKT];
    int t = threadIdx.x;
    for (int i = t; i < NBKT; i += 512) cnt[i] = 0;
    __syncthreads();
    int e0 = blockIdx.x * EPB + t;
    int sv[32], dv[32];
    #pragma unroll
    for (int j = 0; j < 32; ++j) {
        int e = e0 + j * 512;
        if (e < N_EDGES) {
            sv[j] = ei[e];
            dv[j] = ei[N_EDGES + e];
            atomicAdd(&cnt[dv[j] >> 8], 1);
        } else dv[j] = -1;
    }
    __syncthreads();
    for (int i = t; i < NBKT; i += 512) {
        base[i] = atomicAdd(&gcur[i], cnt[i]);
        cnt[i] = 0;
    }
    __syncthreads();
    #pragma unroll
    for (int j = 0; j < 32; ++j) {
        if (dv[j] >= 0) {
            int b = dv[j] >> 8;
            int r = atomicAdd(&cnt[b], 1);
            ebuf[base[b] + r] = (sv[j] << 8) | (dv[j] & 255);
        }
    }
}

// ---------- Pass B: per-bucket histogram -> rc/dis, 8-aligned col, pad-gap dummies ----------

__global__ void __launch_bounds__(256) k_fill2(const int* __restrict__ ebuf,
                                               const int* __restrict__ gcur,
                                               int2* __restrict__ rc,
                                               float* __restrict__ dis,
                                               int* __restrict__ col) {
    __shared__ int cnt[256];
    __shared__ int sc[256];
    __shared__ int exs[256];
    __shared__ int cur[256];
    int b = blockIdx.x, t = threadIdx.x;
    int n0 = b * 256;
    int nrec = gcur[b] - b * CAP;
    const int* eb = ebuf + (size_t)b * CAP;
    int* cw = col + (size_t)b * CAP;
    cnt[t] = 0; cur[t] = 0;
    __syncthreads();
    for (int i = t; i < nrec; i += 256)
        atomicAdd(&cnt[eb[i] & 255], 1);
    __syncthreads();
    int c0 = cnt[t];
    int a8 = (c0 + 7) & ~7;
    sc[t] = a8; __syncthreads();
    for (int off = 1; off < 256; off <<= 1) {
        int u = (t >= off) ? sc[t - off] : 0;
        __syncthreads();
        sc[t] += u;
        __syncthreads();
    }
    int myex = sc[t] - a8;
    exs[t] = myex;
    int n = n0 + t;
    if (n < N_NODES) {
        rc[n] = make_int2(b * CAP + myex, c0);
        dis[n] = rsqrtf((float)(c0 + 1));
    }
    for (int i = myex + c0; i < myex + a8; ++i) cw[i] = N_NODES;
    __syncthreads();
    for (int i = t; i < nrec; i += 256) {
        int rec = eb[i];
        int dl = rec & 255;
        cw[exs[dl] + atomicAdd(&cur[dl], 1)] = rec >> 8;
    }
}

// ---------- layer-1 matmul -> split fp8 half-tables ----------

__global__ void __launch_bounds__(256) k_mm1(const float* __restrict__ inp,
                                             const float* __restrict__ W,
                                             const float* __restrict__ bias,
                                             const float* __restrict__ dis,
                                             unsigned char* __restrict__ tA,
                                             unsigned char* __restrict__ tB) {
    __shared__ float Wl[32][64];
    __shared__ float hs[16][32];
    int t = threadIdx.x;
    for (int i = t; i < 32 * 64; i += 256) Wl[i / 64][i % 64] = W[i];
    int row0 = blockIdx.x * 16;
    for (int i = t; i < 16 * 32; i += 256) {
        int r = row0 + i / 32, k = i % 32;
        hs[i / 32][k] = inp[(size_t)r * 32 + k];
    }
    __syncthreads();
    int c = t & 63, rg = t >> 6;
    float a0 = 0, a1 = 0, a2 = 0, a3 = 0;
    #pragma unroll 4
    for (int k = 0; k < 32; ++k) {
        float wv = Wl[k][c];
        a0 += hs[rg * 4 + 0][k] * wv;
        a1 += hs[rg * 4 + 1][k] * wv;
        a2 += hs[rg * 4 + 2][k] * wv;
        a3 += hs[rg * 4 + 3][k] * wv;
    }
    float bv = bias[c];
    int r = row0 + rg * 4;
    unsigned char* dst = (c < 32) ? tA : tB;
    int cc = c & 31;
    dst[(size_t)(r + 0) * 32 + cc] = f32_to_fp8(FP8_SCALE * dis[r + 0] * (a0 + bv));
    dst[(size_t)(r + 1) * 32 + cc] = f32_to_fp8(FP8_SCALE * dis[r + 1] * (a1 + bv));
    dst[(size_t)(r + 2) * 32 + cc] = f32_to_fp8(FP8_SCALE * dis[r + 2] * (a2 + bv));
    dst[(size_t)(r + 3) * 32 + cc] = f32_to_fp8(FP8_SCALE * dis[r + 3] * (a3 + bv));
}

// ---------- AGG v6: 8 rows/wave x 8 feature-dwords, 8-deep pipeline,
//            high occupancy (launch_bounds min 8 waves/EU) ----------
// agg[row, 32 feats] = tph[row] + sum_e tph[col[e]]   (bf16 out)

__global__ void __launch_bounds__(256, 8) k_agg(const unsigned* __restrict__ tph,
                                                const int2* __restrict__ rc,
                                                const int* __restrict__ col,
                                                unsigned short* __restrict__ agg) {
    int row = blockIdx.x * 32 + (threadIdx.x >> 3);
    int sl = threadIdx.x & 7;
    float a[4] = {0.f, 0.f, 0.f, 0.f};
    float b[4] = {0.f, 0.f, 0.f, 0.f};
    acc4(a, tph[(size_t)row * 8 + sl]);                // self-loop term
    int2 r = rc[row];
    int nit = (r.y + 7) >> 3;                          // 8-edge iterations
    const int* cp = col + r.x;
    if (nit > 0) {
        int4 c0 = *(const int4*)(cp + 0);
        int4 c1 = *(const int4*)(cp + 4);
        for (int it = 1; it < nit; ++it) {
            unsigned v0 = tph[(size_t)c0.x * 8 + sl];
            unsigned v1 = tph[(size_t)c0.y * 8 + sl];
            unsigned v2 = tph[(size_t)c0.z * 8 + sl];
            unsigned v3 = tph[(size_t)c0.w * 8 + sl];
            unsigned v4 = tph[(size_t)c1.x * 8 + sl];
            unsigned v5 = tph[(size_t)c1.y * 8 + sl];
            unsigned v6 = tph[(size_t)c1.z * 8 + sl];
            unsigned v7 = tph[(size_t)c1.w * 8 + sl];
            const int* np = cp + it * 8;               // prefetch next 8 cols
            c0 = *(const int4*)(np + 0);
            c1 = *(const int4*)(np + 4);
            acc4(a, v0); acc4(b, v1); acc4(a, v2); acc4(b, v3);
            acc4(a, v4); acc4(b, v5); acc4(a, v6); acc4(b, v7);
        }
        unsigned v0 = tph[(size_t)c0.x * 8 + sl];
        unsigned v1 = tph[(size_t)c0.y * 8 + sl];
        unsigned v2 = tph[(size_t)c0.z * 8 + sl];
        unsigned v3 = tph[(size_t)c0.w * 8 + sl];
        unsigned v4 = tph[(size_t)c1.x * 8 + sl];
        unsigned v5 = tph[(size_t)c1.y * 8 + sl];
        unsigned v6 = tph[(size_t)c1.z * 8 + sl];
        unsigned v7 = tph[(size_t)c1.w * 8 + sl];
        acc4(a, v0); acc4(b, v1); acc4(a, v2); acc4(b, v3);
        acc4(a, v4); acc4(b, v5); acc4(a, v6); acc4(b, v7);
    }
    ushort4 o;
    o.x = f2bf(a[0] + b[0]); o.y = f2bf(a[1] + b[1]);
    o.z = f2bf(a[2] + b[2]); o.w = f2bf(a[3] + b[3]);
    *(ushort4*)(agg + (size_t)row * 32 + sl * 4) = o;
}

// ---------- MFMA COMBINE: h = relu(dis/S*agg + b); next halves = fp8(S*dis*(h@Wn)) ----------

__global__ void __launch_bounds__(256) k_combm(const unsigned short* __restrict__ aggA,
                                               const unsigned short* __restrict__ aggB,
                                               const float* __restrict__ dis,
                                               const float* __restrict__ bias,
                                               const unsigned short* __restrict__ Wfrag,
                                               unsigned* __restrict__ tA,
                                               unsigned* __restrict__ tB) {
    __shared__ unsigned short h_lds[64][72];          // bf16, padded stride
    int t = threadIdx.x;
    int rowbase = blockIdx.x * 64;
    {
        int row = t >> 2, q = t & 3;
        int grow = rowbase + row;
        if (grow < N_NODES) {
            float f = dis[grow] * FP8_INV;
            #pragma unroll
            for (int i = 0; i < 4; ++i) {
                int c0 = q * 16 + i * 4;
                const unsigned short* src = ((c0 < 32) ? aggA : aggB) +
                                            (size_t)grow * 32 + (c0 & 31);
                ushort4 v = *(const ushort4*)src;
                short4 o;
                o.x = (short)f2bf(fmaxf(f * __uint_as_float((unsigned)v.x << 16) + bias[c0 + 0], 0.f));
                o.y = (short)f2bf(fmaxf(f * __uint_as_float((unsigned)v.y << 16) + bias[c0 + 1], 0.f));
                o.z = (short)f2bf(fmaxf(f * __uint_as_float((unsigned)v.z << 16) + bias[c0 + 2], 0.f));
                o.w = (short)f2bf(fmaxf(f * __uint_as_float((unsigned)v.w << 16) + bias[c0 + 3], 0.f));
                *(short4*)&h_lds[row][c0] = o;
            }
        } else {
            #pragma unroll
            for (int i = 0; i < 4; ++i)
                *(short4*)&h_lds[row][q * 16 + i * 4] = make_short4(0, 0, 0, 0);
        }
    }
    __syncthreads();
    int w = t >> 6, l = t & 63;
    f32x4 acc[4] = {{0,0,0,0}, {0,0,0,0}, {0,0,0,0}, {0,0,0,0}};
    const bf16x8* wf = (const bf16x8*)Wfrag;
    #pragma unroll
    for (int kt = 0; kt < 2; ++kt) {
        bf16x8 bfr = *(const bf16x8*)&h_lds[w * 16 + (l & 15)][kt * 32 + ((l >> 4) << 3)];
        #pragma unroll
        for (int mt = 0; mt < 4; ++mt) {
            bf16x8 afr = wf[(kt * 4 + mt) * 64 + l];
            acc[mt] = __builtin_amdgcn_mfma_f32_16x16x32_bf16(afr, bfr, acc[mt], 0, 0, 0);
        }
    }
    int hrow = rowbase + w * 16 + (l & 15);
    if (hrow < N_NODES) {
        float sc2 = FP8_SCALE * dis[hrow];
        #pragma unroll
        for (int mt = 0; mt < 4; ++mt) {
            int colbase = mt * 16 + ((l >> 4) << 2);
            unsigned d = pack4_fp8(sc2 * acc[mt][0], sc2 * acc[mt][1],
                                   sc2 * acc[mt][2], sc2 * acc[mt][3]);
            if (colbase < 32) tA[(size_t)hrow * 8 + (colbase >> 2)] = d;
            else              tB[(size_t)hrow * 8 + ((colbase - 32) >> 2)] = d;
        }
    }
}

// ---------- fused last layer: h = relu(dis/S*agg + b4) -> mean pool -> MLP head ----------

__global__ void __launch_bounds__(256) k_poolhead(const unsigned short* __restrict__ aggA,
                                                  const unsigned short* __restrict__ aggB,
                                                  const float* __restrict__ dis,
                                                  const float* __restrict__ bias,
                                                  const int* __restrict__ batch,
                                                  const float* __restrict__ Wr1, const float* __restrict__ br1,
                                                  const float* __restrict__ Wr2, const float* __restrict__ br2,
                                                  const float* __restrict__ Wr3, const float* __restrict__ br3,
                                                  float* __restrict__ out) {
    __shared__ float part[4][64];
    __shared__ float p[64], r1[32], r2[16], lg[10];
    __shared__ int seg[2];
    int g = blockIdx.x, t = threadIdx.x;
    if (t < 2) {
        int key = g + t;
        int lo = 0, hi = N_NODES;
        while (lo < hi) { int m = (lo + hi) >> 1; if (batch[m] < key) lo = m + 1; else hi = m; }
        seg[t] = lo;
    }
    __syncthreads();
    int start = seg[0], end = seg[1];
    int w = t >> 6, grp = (t >> 4) & 3, sl = t & 15;
    int slh = sl & 7;
    const unsigned short* ag = (sl < 8) ? aggA : aggB;
    float b0 = bias[sl * 4 + 0], b1 = bias[sl * 4 + 1];
    float b2 = bias[sl * 4 + 2], b3 = bias[sl * 4 + 3];
    float a[4] = {0.f, 0.f, 0.f, 0.f};
    for (int r = start + w * 4 + grp; r < end; r += 16) {
        ushort4 v = *(const ushort4*)(ag + (size_t)r * 32 + slh * 4);
        float s = dis[r] * FP8_INV;
        a[0] += fmaxf(s * __uint_as_float((unsigned)v.x << 16) + b0, 0.f);
        a[1] += fmaxf(s * __uint_as_float((unsigned)v.y << 16) + b1, 0.f);
        a[2] += fmaxf(s * __uint_as_float((unsigned)v.z << 16) + b2, 0.f);
        a[3] += fmaxf(s * __uint_as_float((unsigned)v.w << 16) + b3, 0.f);
    }
    #pragma unroll
    for (int j = 0; j < 4; ++j) {
        a[j] += __shfl_xor(a[j], 16);
        a[j] += __shfl_xor(a[j], 32);
    }
    if (sl == (t & 63)) {
        #pragma unroll
        for (int j = 0; j < 4; ++j) part[w][sl * 4 + j] = a[j];
    }
    __syncthreads();
    if (t < 64) {
        float s = part[0][t] + part[1][t] + part[2][t] + part[3][t];
        float c = fmaxf((float)(end - start), 1.f);
        p[t] = s / c;
    }
    __syncthreads();
    if (t < 32) {
        float acc = br1[t];
        for (int k = 0; k < 64; ++k) acc += p[k] * Wr1[k * 32 + t];
        r1[t] = fmaxf(acc, 0.f);
    }
    __syncthreads();
    if (t < 16) {
        float acc = br2[t];
        for (int k = 0; k < 32; ++k) acc += r1[k] * Wr2[k * 16 + t];
        r2[t] = fmaxf(acc, 0.f);
    }
    __syncthreads();
    if (t < 10) {
        float acc = br3[t];
        for (int k = 0; k < 16; ++k) acc += r2[k] * Wr3[k * 10 + t];
        lg[t] = acc;
    }
    __syncthreads();
    if (t < 10) {
        float m = -1e30f;
        for (int j = 0; j < 10; ++j) m = fmaxf(m, lg[j]);
        float s = 0.f;
        for (int j = 0; j < 10; ++j) s += expf(lg[j] - m);
        out[g * 10 + t] = lg[t] - m - logf(s);
    }
}

extern "C" void kernel_launch(void* const* d_in, const int* in_sizes, int n_in,
                              void* d_out, int out_size, void* d_ws, size_t ws_size,
                              hipStream_t stream) {
    const float* x     = (const float*)d_in[0];
    const int*   ei    = (const int*)d_in[1];
    const int*   batch = (const int*)d_in[2];
    const float* W_emb = (const float*)d_in[4];
    const float* b_emb = (const float*)d_in[5];
    const float* W1    = (const float*)d_in[6];
    const float* b1    = (const float*)d_in[7];
    const float* W2    = (const float*)d_in[8];
    const float* b2    = (const float*)d_in[9];
    const float* W3    = (const float*)d_in[10];
    const float* b3    = (const float*)d_in[11];
    const float* W4    = (const float*)d_in[12];
    const float* b4    = (const float*)d_in[13];
    const float* Wr1   = (const float*)d_in[14];
    const float* br1   = (const float*)d_in[15];
    const float* Wr2   = (const float*)d_in[16];
    const float* br2   = (const float*)d_in[17];
    const float* Wr3   = (const float*)d_in[18];
    const float* br3   = (const float*)d_in[19];
    float* out = (float*)d_out;

    char* ws = (char*)d_ws;
    size_t off = 0;
    auto alloc = [&](size_t b) { char* p = ws + off; off += (b + 511) & ~(size_t)511; return p; };
    size_t TBYTES = (size_t)(N_NODES + 1) * 32;
    int*   col    = (int*)  alloc((size_t)NBKT * CAP * 4);     // 16.4 MB
    int*   ebuf   = (int*)  alloc((size_t)NBKT * CAP * 4);
    unsigned char* T0a = (unsigned char*)alloc(TBYTES);        // fp8 half-tables (+dummy row)
    unsigned char* T0b = (unsigned char*)alloc(TBYTES);
    unsigned char* T1a = (unsigned char*)alloc(TBYTES);
    unsigned char* T1b = (unsigned char*)alloc(TBYTES);
    unsigned short* aggA = (unsigned short*)alloc((size_t)N_NODES * 32 * 2);  // bf16
    unsigned short* aggB = (unsigned short*)alloc((size_t)N_NODES * 32 * 2);
    int2*  rc     = (int2*) alloc((size_t)N_NODES * 8);
    float* dis    = (float*)alloc((size_t)N_NODES * 4);
    int*   gcur   = (int*)  alloc((size_t)NBKT * 4);
    float* Wc     = (float*)alloc(32 * 64 * 4);
    float* bc     = (float*)alloc(64 * 4);
    unsigned short* Wfrag = (unsigned short*)alloc(3 * 4096 * 2);

    k_setup<<<5, 256, 0, stream>>>(W_emb, b_emb, W1, W2, W3, W4, Wc, bc, Wfrag, gcur,
                                   (unsigned*)T0a, (unsigned*)T0b,
                                   (unsigned*)T1a, (unsigned*)T1b);
    k_bucket<<<NBLK_A, 512, 0, stream>>>(ei, gcur, ebuf);
    k_fill2<<<NBKT, 256, 0, stream>>>(ebuf, gcur, rc, dis, col);

    int nbm = N_NODES / 16;        // 6250
    int nba = N_NODES / 32;        // 3125
    int nbc = (N_NODES + 63) / 64; // 1563

    k_mm1<<<nbm, 256, 0, stream>>>(x, Wc, bc, dis, T0a, T0b);

    const float* lb[4] = {b1, b2, b3, b4};
    unsigned char* cura = T0a; unsigned char* curb = T0b;
    unsigned char* nxta = T1a; unsigned char* nxtb = T1b;
    for (int l = 0; l < 4; ++l) {
        k_agg<<<nba, 256, 0, stream>>>((const unsigned*)cura, rc, col, aggA);
        k_agg<<<nba, 256, 0, stream>>>((const unsigned*)curb, rc, col, aggB);
        if (l < 3) {
            k_combm<<<nbc, 256, 0, stream>>>(aggA, aggB, dis, lb[l], Wfrag + (size_t)l * 4096,
                                             (unsigned*)nxta, (unsigned*)nxtb);
            unsigned char* ta = cura; cura = nxta; nxta = ta;
            unsigned char* tb = curb; curb = nxtb; nxtb = tb;
        }
    }
    k_poolhead<<<N_GRAPHS, 256, 0, stream>>>(aggA, aggB, dis, b4, batch,
                                             Wr1, br1, Wr2, br2, Wr3, br3, out);
}

// Round 13
// 246.087 us; speedup vs baseline: 2.1829x; 1.3070x over previous
//
#include <hip/hip_runtime.h>
#include <hip/hip_bf16.h>

typedef __hip_bfloat16 bf16;
typedef short bf16x8 __attribute__((ext_vector_type(8)));
typedef float f32x4 __attribute__((ext_vector_type(4)));

#define N_NODES 100000
#define N_EDGES 3200000
#define N_GRAPHS 512
#define NBKT    ((N_NODES + 255) / 256)               // 391 buckets of 256 nodes
#define CAP     10496                                 // slots per bucket window (8-aligned)
#define EPB     16384                                 // edges per k_bucket block
#define NBLK_A  ((N_EDGES + EPB - 1) / EPB)           // 196
#define FP4_SCALE 16.0f
#define FP4_INV   (1.0f / 16.0f)

// ---------- fp8 helpers (decode backend for fp4 path) ----------

__device__ inline float fp8_to_f32(unsigned int b) {
    unsigned s = (b >> 7) & 1, e = (b >> 3) & 15, m = b & 7;
    float v = (e == 0) ? (float)m * 0.001953125f
                       : __uint_as_float(((e + 120u) << 23) | (m << 20));
    return s ? -v : v;
}

__device__ inline void acc4(float* a, unsigned v) {
#if __has_builtin(__builtin_amdgcn_cvt_pk_f32_fp8)
    typedef float f32x2 __attribute__((ext_vector_type(2)));
    f32x2 lo = __builtin_amdgcn_cvt_pk_f32_fp8((int)v, false);
    f32x2 hi = __builtin_amdgcn_cvt_pk_f32_fp8((int)v, true);
    a[0] += lo.x; a[1] += lo.y; a[2] += hi.x; a[3] += hi.y;
#elif __has_builtin(__builtin_amdgcn_cvt_f32_fp8)
    a[0] += __builtin_amdgcn_cvt_f32_fp8(v, 0);
    a[1] += __builtin_amdgcn_cvt_f32_fp8(v, 1);
    a[2] += __builtin_amdgcn_cvt_f32_fp8(v, 2);
    a[3] += __builtin_amdgcn_cvt_f32_fp8(v, 3);
#else
    a[0] += fp8_to_f32(v & 0xFF);
    a[1] += fp8_to_f32((v >> 8) & 0xFF);
    a[2] += fp8_to_f32((v >> 16) & 0xFF);
    a[3] += fp8_to_f32((v >> 24) & 0xFF);
#endif
}

// ---------- fp4 e2m1 decode: 8 nibbles -> a[4] (even feats) + b[4] (odd feats) ----------
// mag LUT (fp8 e4m3 bytes): 0,0.5,1,1.5,2,3,4,6 -> 00,30,38,3C,40,44,48,4C

__device__ inline void accf4(float* a, float* b, unsigned d) {
#if __has_builtin(__builtin_amdgcn_perm)
    unsigned lo8 = __builtin_amdgcn_perm(0x4C484440u, 0x3C383000u, d & 0x07070707u)
                 | ((d & 0x08080808u) << 4);
    unsigned hi8 = __builtin_amdgcn_perm(0x4C484440u, 0x3C383000u, (d >> 4) & 0x07070707u)
                 | (d & 0x80808080u);
#else
    unsigned lo8 = 0, hi8 = 0;
    #pragma unroll
    for (int i = 0; i < 4; ++i) {
        unsigned ln = (d >> (8 * i)) & 7u, hs_ = (d >> (8 * i)) & 0x80u;
        unsigned hn = (d >> (8 * i + 4)) & 7u, ls_ = ((d >> (8 * i)) & 8u) << 4;
        unsigned lb = (ln < 2) ? ln * 0x30u : (0x30u + (ln << 2));
        unsigned hb = (hn < 2) ? hn * 0x30u : (0x30u + (hn << 2));
        lo8 |= (lb | ls_) << (8 * i);
        hi8 |= (hb | hs_) << (8 * i);
    }
#endif
    acc4(a, lo8);
    acc4(b, hi8);
}

// ---------- fp4 encode: f32 -> nibble (RNE over the e2m1 grid) ----------

__device__ inline unsigned fp4n(float v) {
    unsigned s = (__float_as_uint(v) >> 28) & 8u;
    float x = fabsf(v);
    unsigned n = (unsigned)(x >= 0.25f) + (x >= 0.75f) + (x >= 1.25f) + (x >= 1.75f)
               + (x >= 2.5f) + (x >= 3.5f) + (x >= 5.0f);
    return s | n;
}

__device__ inline unsigned short f2bf(float x) {
    unsigned u = __float_as_uint(x);
    return (unsigned short)((u + 0x7FFF + ((u >> 16) & 1)) >> 16);
}

// ---------- setup: Wc/bc, Wfrag, gcur, dummy rows — one kernel ----------

__global__ void k_setup(const float* __restrict__ W_emb, const float* __restrict__ b_emb,
                        const float* __restrict__ W1, const float* __restrict__ W2,
                        const float* __restrict__ W3, const float* __restrict__ W4,
                        float* __restrict__ Wc, float* __restrict__ bc,
                        unsigned short* __restrict__ Wfrag, int* __restrict__ gcur,
                        unsigned* __restrict__ ta, unsigned* __restrict__ tb) {
    int blk = blockIdx.x, t = threadIdx.x;
    if (blk == 0) {                       // folded embedding: Wc = W_emb@W1, bc = b_emb@W1
        for (int i = t; i < 32 * 64; i += 256) {
            int a = i / 64, b = i % 64;
            float acc = 0.f;
            for (int k = 0; k < 64; ++k) acc += W_emb[a * 64 + k] * W1[k * 64 + b];
            Wc[i] = acc;
        }
        if (t < 64) {
            float acc = 0.f;
            for (int k = 0; k < 64; ++k) acc += b_emb[k] * W1[k * 64 + t];
            bc[t] = acc;
        }
    } else if (blk <= 3) {                // MFMA A-fragments of Wn^T
        const float* W = (blk == 1) ? W2 : (blk == 2) ? W3 : W4;
        unsigned short* dst = Wfrag + (size_t)(blk - 1) * 4096;
        for (int i = 0; i < 16; ++i) {
            int flat = t * 16 + i;
            int j = flat & 7, lane = (flat >> 3) & 63, mt = (flat >> 9) & 3, kt = flat >> 11;
            int m = mt * 16 + (lane & 15);
            int k = kt * 32 + ((lane >> 4) << 3) + j;
            dst[flat] = f2bf(W[k * 64 + m]);
        }
    } else {                              // gcur init + dummy gather rows
        for (int b = t; b < NBKT; b += 256) gcur[b] = b * CAP;
        if (t < 8) {
            size_t o = (size_t)N_NODES * 8 + t;
            ta[o] = 0; tb[o] = 0;
        }
    }
}

// ---------- Pass A: bin edges by dst>>8 into fixed-CAP bucket windows ----------

__global__ void __launch_bounds__(512) k_bucket(const int* __restrict__ ei,
                                                int* __restrict__ gcur,
                                                int* __restrict__ ebuf) {
    __shared__ int cnt[NBKT];
    __shared__ int base[NBKT];
    int t = threadIdx.x;
    for (int i = t; i < NBKT; i += 512) cnt[i] = 0;
    __syncthreads();
    int e0 = blockIdx.x * EPB + t;
    int sv[32], dv[32];
    #pragma unroll
    for (int j = 0; j < 32; ++j) {
        int e = e0 + j * 512;
        if (e < N_EDGES) {
            sv[j] = ei[e];
            dv[j] = ei[N_EDGES + e];
            atomicAdd(&cnt[dv[j] >> 8], 1);
        } else dv[j] = -1;
    }
    __syncthreads();
    for (int i = t; i < NBKT; i += 512) {
        base[i] = atomicAdd(&gcur[i], cnt[i]);
        cnt[i] = 0;
    }
    __syncthreads();
    #pragma unroll
    for (int j = 0; j < 32; ++j) {
        if (dv[j] >= 0) {
            int b = dv[j] >> 8;
            int r = atomicAdd(&cnt[b], 1);
            ebuf[base[b] + r] = (sv[j] << 8) | (dv[j] & 255);
        }
    }
}

// ---------- Pass B: per-bucket histogram -> rc/dis, 8-aligned col, pad-gap dummies ----------

__global__ void __launch_bounds__(256) k_fill2(const int* __restrict__ ebuf,
                                               const int* __restrict__ gcur,
                                               int2* __restrict__ rc,
                                               float* __restrict__ dis,
                                               int* __restrict__ col) {
    __shared__ int cnt[256];
    __shared__ int sc[256];
    __shared__ int exs[256];
    __shared__ int cur[256];
    int b = blockIdx.x, t = threadIdx.x;
    int n0 = b * 256;
    int nrec = gcur[b] - b * CAP;
    const int* eb = ebuf + (size_t)b * CAP;
    int* cw = col + (size_t)b * CAP;
    cnt[t] = 0; cur[t] = 0;
    __syncthreads();
    for (int i = t; i < nrec; i += 256)
        atomicAdd(&cnt[eb[i] & 255], 1);
    __syncthreads();
    int c0 = cnt[t];
    int a8 = (c0 + 7) & ~7;
    sc[t] = a8; __syncthreads();
    for (int off = 1; off < 256; off <<= 1) {
        int u = (t >= off) ? sc[t - off] : 0;
        __syncthreads();
        sc[t] += u;
        __syncthreads();
    }
    int myex = sc[t] - a8;
    exs[t] = myex;
    int n = n0 + t;
    if (n < N_NODES) {
        rc[n] = make_int2(b * CAP + myex, c0);
        dis[n] = rsqrtf((float)(c0 + 1));
    }
    for (int i = myex + c0; i < myex + a8; ++i) cw[i] = N_NODES;
    __syncthreads();
    for (int i = t; i < nrec; i += 256) {
        int rec = eb[i];
        int dl = rec & 255;
        cw[exs[dl] + atomicAdd(&cur[dl], 1)] = rec >> 8;
    }
}

// ---------- layer-1 matmul -> fp4 table (nibble-packed, 32B rows) ----------

__global__ void __launch_bounds__(256) k_mm1(const float* __restrict__ inp,
                                             const float* __restrict__ W,
                                             const float* __restrict__ bias,
                                             const float* __restrict__ dis,
                                             unsigned char* __restrict__ T) {
    __shared__ float Wl[32][64];
    __shared__ float hs[16][32];
    int t = threadIdx.x;
    for (int i = t; i < 32 * 64; i += 256) Wl[i / 64][i % 64] = W[i];
    int row0 = blockIdx.x * 16;
    for (int i = t; i < 16 * 32; i += 256) {
        int r = row0 + i / 32, k = i % 32;
        hs[i / 32][k] = inp[(size_t)r * 32 + k];
    }
    __syncthreads();
    int c = t & 63, rg = t >> 6;
    float a0 = 0, a1 = 0, a2 = 0, a3 = 0;
    #pragma unroll 4
    for (int k = 0; k < 32; ++k) {
        float wv = Wl[k][c];
        a0 += hs[rg * 4 + 0][k] * wv;
        a1 += hs[rg * 4 + 1][k] * wv;
        a2 += hs[rg * 4 + 2][k] * wv;
        a3 += hs[rg * 4 + 3][k] * wv;
    }
    float bv = bias[c];
    int r = row0 + rg * 4;
    unsigned n0 = fp4n(FP4_SCALE * dis[r + 0] * (a0 + bv));
    unsigned n1 = fp4n(FP4_SCALE * dis[r + 1] * (a1 + bv));
    unsigned n2 = fp4n(FP4_SCALE * dis[r + 2] * (a2 + bv));
    unsigned n3 = fp4n(FP4_SCALE * dis[r + 3] * (a3 + bv));
    unsigned p0 = __shfl_xor(n0, 1), p1 = __shfl_xor(n1, 1);
    unsigned p2 = __shfl_xor(n2, 1), p3 = __shfl_xor(n3, 1);
    if ((c & 1) == 0) {                      // even col stores the packed byte
        size_t boff = (size_t)(c >> 1);
        T[(size_t)(r + 0) * 32 + boff] = (unsigned char)(n0 | (p0 << 4));
        T[(size_t)(r + 1) * 32 + boff] = (unsigned char)(n1 | (p1 << 4));
        T[(size_t)(r + 2) * 32 + boff] = (unsigned char)(n2 | (p2 << 4));
        T[(size_t)(r + 3) * 32 + boff] = (unsigned char)(n3 | (p3 << 4));
    }
}

// ---------- AGG fp4: full 64-feature rows (32B), one dispatch per layer ----------
// 8 rows/wave x 8 feature-dwords; 8-deep pipelined gathers; a=even feats, b=odd feats

__global__ void __launch_bounds__(256, 8) k_agg(const unsigned* __restrict__ tph,
                                                const int2* __restrict__ rc,
                                                const int* __restrict__ col,
                                                unsigned short* __restrict__ agg) {
    int row = blockIdx.x * 32 + (threadIdx.x >> 3);
    int sl = threadIdx.x & 7;
    float a[4] = {0.f, 0.f, 0.f, 0.f};
    float b[4] = {0.f, 0.f, 0.f, 0.f};
    accf4(a, b, tph[(size_t)row * 8 + sl]);            // self-loop term
    int2 r = rc[row];
    int nit = (r.y + 7) >> 3;                          // 8-edge iterations
    const int* cp = col + r.x;
    if (nit > 0) {
        int4 c0 = *(const int4*)(cp + 0);
        int4 c1 = *(const int4*)(cp + 4);
        for (int it = 1; it < nit; ++it) {
            unsigned v0 = tph[(size_t)c0.x * 8 + sl];
            unsigned v1 = tph[(size_t)c0.y * 8 + sl];
            unsigned v2 = tph[(size_t)c0.z * 8 + sl];
            unsigned v3 = tph[(size_t)c0.w * 8 + sl];
            unsigned v4 = tph[(size_t)c1.x * 8 + sl];
            unsigned v5 = tph[(size_t)c1.y * 8 + sl];
            unsigned v6 = tph[(size_t)c1.z * 8 + sl];
            unsigned v7 = tph[(size_t)c1.w * 8 + sl];
            const int* np = cp + it * 8;               // prefetch next 8 cols
            c0 = *(const int4*)(np + 0);
            c1 = *(const int4*)(np + 4);
            accf4(a, b, v0); accf4(a, b, v1); accf4(a, b, v2); accf4(a, b, v3);
            accf4(a, b, v4); accf4(a, b, v5); accf4(a, b, v6); accf4(a, b, v7);
        }
        unsigned v0 = tph[(size_t)c0.x * 8 + sl];
        unsigned v1 = tph[(size_t)c0.y * 8 + sl];
        unsigned v2 = tph[(size_t)c0.z * 8 + sl];
        unsigned v3 = tph[(size_t)c0.w * 8 + sl];
        unsigned v4 = tph[(size_t)c1.x * 8 + sl];
        unsigned v5 = tph[(size_t)c1.y * 8 + sl];
        unsigned v6 = tph[(size_t)c1.z * 8 + sl];
        unsigned v7 = tph[(size_t)c1.w * 8 + sl];
        accf4(a, b, v0); accf4(a, b, v1); accf4(a, b, v2); accf4(a, b, v3);
        accf4(a, b, v4); accf4(a, b, v5); accf4(a, b, v6); accf4(a, b, v7);
    }
    uint4 o;                                           // interleave even/odd -> features sl*8..+7
    o.x = (unsigned)f2bf(a[0]) | ((unsigned)f2bf(b[0]) << 16);
    o.y = (unsigned)f2bf(a[1]) | ((unsigned)f2bf(b[1]) << 16);
    o.z = (unsigned)f2bf(a[2]) | ((unsigned)f2bf(b[2]) << 16);
    o.w = (unsigned)f2bf(a[3]) | ((unsigned)f2bf(b[3]) << 16);
    *(uint4*)(agg + (size_t)row * 64 + sl * 8) = o;
}

// ---------- MFMA COMBINE: h = relu(dis/S*agg + b); next table = fp4(S*dis*(h@Wn)) ----------

__global__ void __launch_bounds__(256) k_combm(const unsigned short* __restrict__ agg,
                                               const float* __restrict__ dis,
                                               const float* __restrict__ bias,
                                               const unsigned short* __restrict__ Wfrag,
                                               unsigned char* __restrict__ T) {
    __shared__ unsigned short h_lds[64][72];          // bf16, padded stride
    int t = threadIdx.x;
    int rowbase = blockIdx.x * 64;
    {
        int row = t >> 2, q = t & 3;
        int grow = rowbase + row;
        if (grow < N_NODES) {
            float f = dis[grow] * FP4_INV;
            #pragma unroll
            for (int i = 0; i < 4; ++i) {
                int c0 = q * 16 + i * 4;
                ushort4 v = *(const ushort4*)(agg + (size_t)grow * 64 + c0);
                short4 o;
                o.x = (short)f2bf(fmaxf(f * __uint_as_float((unsigned)v.x << 16) + bias[c0 + 0], 0.f));
                o.y = (short)f2bf(fmaxf(f * __uint_as_float((unsigned)v.y << 16) + bias[c0 + 1], 0.f));
                o.z = (short)f2bf(fmaxf(f * __uint_as_float((unsigned)v.z << 16) + bias[c0 + 2], 0.f));
                o.w = (short)f2bf(fmaxf(f * __uint_as_float((unsigned)v.w << 16) + bias[c0 + 3], 0.f));
                *(short4*)&h_lds[row][c0] = o;
            }
        } else {
            #pragma unroll
            for (int i = 0; i < 4; ++i)
                *(short4*)&h_lds[row][q * 16 + i * 4] = make_short4(0, 0, 0, 0);
        }
    }
    __syncthreads();
    int w = t >> 6, l = t & 63;
    f32x4 acc[4] = {{0,0,0,0}, {0,0,0,0}, {0,0,0,0}, {0,0,0,0}};
    const bf16x8* wf = (const bf16x8*)Wfrag;
    #pragma unroll
    for (int kt = 0; kt < 2; ++kt) {
        bf16x8 bfr = *(const bf16x8*)&h_lds[w * 16 + (l & 15)][kt * 32 + ((l >> 4) << 3)];
        #pragma unroll
        for (int mt = 0; mt < 4; ++mt) {
            bf16x8 afr = wf[(kt * 4 + mt) * 64 + l];
            acc[mt] = __builtin_amdgcn_mfma_f32_16x16x32_bf16(afr, bfr, acc[mt], 0, 0, 0);
        }
    }
    int hrow = rowbase + w * 16 + (l & 15);
    if (hrow < N_NODES) {
        float sc2 = FP4_SCALE * dis[hrow];
        #pragma unroll
        for (int mt = 0; mt < 4; ++mt) {
            int colbase = mt * 16 + ((l >> 4) << 2);
            unsigned short v = (unsigned short)(fp4n(sc2 * acc[mt][0])
                               | (fp4n(sc2 * acc[mt][1]) << 4)
                               | (fp4n(sc2 * acc[mt][2]) << 8)
                               | (fp4n(sc2 * acc[mt][3]) << 12));
            *(unsigned short*)(T + (size_t)hrow * 32 + (colbase >> 1)) = v;
        }
    }
}

// ---------- fused last layer: h = relu(dis/S*agg + b4) -> mean pool -> MLP head ----------

__global__ void __launch_bounds__(256) k_poolhead(const unsigned short* __restrict__ agg,
                                                  const float* __restrict__ dis,
                                                  const float* __restrict__ bias,
                                                  const int* __restrict__ batch,
                                                  const float* __restrict__ Wr1, const float* __restrict__ br1,
                                                  const float* __restrict__ Wr2, const float* __restrict__ br2,
                                                  const float* __restrict__ Wr3, const float* __restrict__ br3,
                                                  float* __restrict__ out) {
    __shared__ float part[4][64];
    __shared__ float p[64], r1[32], r2[16], lg[10];
    __shared__ int seg[2];
    int g = blockIdx.x, t = threadIdx.x;
    if (t < 2) {
        int key = g + t;
        int lo = 0, hi = N_NODES;
        while (lo < hi) { int m = (lo + hi) >> 1; if (batch[m] < key) lo = m + 1; else hi = m; }
        seg[t] = lo;
    }
    __syncthreads();
    int start = seg[0], end = seg[1];
    int w = t >> 6, grp = (t >> 4) & 3, sl = t & 15;
    float b0 = bias[sl * 4 + 0], b1 = bias[sl * 4 + 1];
    float b2 = bias[sl * 4 + 2], b3 = bias[sl * 4 + 3];
    float a[4] = {0.f, 0.f, 0.f, 0.f};
    for (int r = start + w * 4 + grp; r < end; r += 16) {
        ushort4 v = *(const ushort4*)(agg + (size_t)r * 64 + sl * 4);
        float s = dis[r] * FP4_INV;
        a[0] += fmaxf(s * __uint_as_float((unsigned)v.x << 16) + b0, 0.f);
        a[1] += fmaxf(s * __uint_as_float((unsigned)v.y << 16) + b1, 0.f);
        a[2] += fmaxf(s * __uint_as_float((unsigned)v.z << 16) + b2, 0.f);
        a[3] += fmaxf(s * __uint_as_float((unsigned)v.w << 16) + b3, 0.f);
    }
    #pragma unroll
    for (int j = 0; j < 4; ++j) {
        a[j] += __shfl_xor(a[j], 16);
        a[j] += __shfl_xor(a[j], 32);
    }
    if (sl == (t & 63)) {
        #pragma unroll
        for (int j = 0; j < 4; ++j) part[w][sl * 4 + j] = a[j];
    }
    __syncthreads();
    if (t < 64) {
        float s = part[0][t] + part[1][t] + part[2][t] + part[3][t];
        float c = fmaxf((float)(end - start), 1.f);
        p[t] = s / c;
    }
    __syncthreads();
    if (t < 32) {
        float acc = br1[t];
        for (int k = 0; k < 64; ++k) acc += p[k] * Wr1[k * 32 + t];
        r1[t] = fmaxf(acc, 0.f);
    }
    __syncthreads();
    if (t < 16) {
        float acc = br2[t];
        for (int k = 0; k < 32; ++k) acc += r1[k] * Wr2[k * 16 + t];
        r2[t] = fmaxf(acc, 0.f);
    }
    __syncthreads();
    if (t < 10) {
        float acc = br3[t];
        for (int k = 0; k < 16; ++k) acc += r2[k] * Wr3[k * 10 + t];
        lg[t] = acc;
    }
    __syncthreads();
    if (t < 10) {
        float m = -1e30f;
        for (int j = 0; j < 10; ++j) m = fmaxf(m, lg[j]);
        float s = 0.f;
        for (int j = 0; j < 10; ++j) s += expf(lg[j] - m);
        out[g * 10 + t] = lg[t] - m - logf(s);
    }
}

extern "C" void kernel_launch(void* const* d_in, const int* in_sizes, int n_in,
                              void* d_out, int out_size, void* d_ws, size_t ws_size,
                              hipStream_t stream) {
    const float* x     = (const float*)d_in[0];
    const int*   ei    = (const int*)d_in[1];
    const int*   batch = (const int*)d_in[2];
    const float* W_emb = (const float*)d_in[4];
    const float* b_emb = (const float*)d_in[5];
    const float* W1    = (const float*)d_in[6];
    const float* b1    = (const float*)d_in[7];
    const float* W2    = (const float*)d_in[8];
    const float* b2    = (const float*)d_in[9];
    const float* W3    = (const float*)d_in[10];
    const float* b3    = (const float*)d_in[11];
    const float* W4    = (const float*)d_in[12];
    const float* b4    = (const float*)d_in[13];
    const float* Wr1   = (const float*)d_in[14];
    const float* br1   = (const float*)d_in[15];
    const float* Wr2   = (const float*)d_in[16];
    const float* br2   = (const float*)d_in[17];
    const float* Wr3   = (const float*)d_in[18];
    const float* br3   = (const float*)d_in[19];
    float* out = (float*)d_out;

    char* ws = (char*)d_ws;
    size_t off = 0;
    auto alloc = [&](size_t b) { char* p = ws + off; off += (b + 511) & ~(size_t)511; return p; };
    size_t TBYTES = (size_t)(N_NODES + 1) * 32;
    int*   col    = (int*)  alloc((size_t)NBKT * CAP * 4);     // 16.4 MB
    int*   ebuf   = (int*)  alloc((size_t)NBKT * CAP * 4);
    unsigned char* Ta = (unsigned char*)alloc(TBYTES);         // fp4 tables (+dummy row)
    unsigned char* Tb = (unsigned char*)alloc(TBYTES);
    unsigned short* aggb = (unsigned short*)alloc((size_t)N_NODES * 64 * 2);  // bf16
    int2*  rc     = (int2*) alloc((size_t)N_NODES * 8);
    float* dis    = (float*)alloc((size_t)N_NODES * 4);
    int*   gcur   = (int*)  alloc((size_t)NBKT * 4);
    float* Wc     = (float*)alloc(32 * 64 * 4);
    float* bc     = (float*)alloc(64 * 4);
    unsigned short* Wfrag = (unsigned short*)alloc(3 * 4096 * 2);

    k_setup<<<5, 256, 0, stream>>>(W_emb, b_emb, W1, W2, W3, W4, Wc, bc, Wfrag, gcur,
                                   (unsigned*)Ta, (unsigned*)Tb);
    k_bucket<<<NBLK_A, 512, 0, stream>>>(ei, gcur, ebuf);
    k_fill2<<<NBKT, 256, 0, stream>>>(ebuf, gcur, rc, dis, col);

    int nbm = N_NODES / 16;        // 6250
    int nba = N_NODES / 32;        // 3125
    int nbc = (N_NODES + 63) / 64; // 1563

    k_mm1<<<nbm, 256, 0, stream>>>(x, Wc, bc, dis, Ta);

    const float* lb[4] = {b1, b2, b3, b4};
    unsigned char* cur = Ta;
    unsigned char* nxt = Tb;
    for (int l = 0; l < 4; ++l) {
        k_agg<<<nba, 256, 0, stream>>>((const unsigned*)cur, rc, col, aggb);
        if (l < 3) {
            k_combm<<<nbc, 256, 0, stream>>>(aggb, dis, lb[l], Wfrag + (size_t)l * 4096, nxt);
            unsigned char* tmp = cur; cur = nxt; nxt = tmp;
        }
    }
    k_poolhead<<<N_GRAPHS, 256, 0, stream>>>(aggb, dis, b4, batch,
                                             Wr1, br1, Wr2, br2, Wr3, br3, out);
}

// Round 14
// 232.752 us; speedup vs baseline: 2.3080x; 1.0573x over previous
//
#include <hip/hip_runtime.h>
#include <hip/hip_bf16.h>

typedef __hip_bfloat16 bf16;
typedef short bf16x8 __attribute__((ext_vector_type(8)));
typedef float f32x4 __attribute__((ext_vector_type(4)));
typedef float f32x2 __attribute__((ext_vector_type(2)));

#define N_NODES 100000
#define N_EDGES 3200000
#define N_GRAPHS 512
#define NBKT    ((N_NODES + 255) / 256)               // 391 buckets of 256 nodes
#define CAP     10496                                 // slots per bucket window (8-aligned)
#define EPB     16384                                 // edges per k_bucket block
#define NBLK_A  ((N_EDGES + EPB - 1) / EPB)           // 196
#define FP4_SCALE 16.0f
#define FP4_INV   (1.0f / 16.0f)

// ---------- fp8 decode backend ----------

__device__ inline float fp8_to_f32(unsigned int b) {
    unsigned s = (b >> 7) & 1, e = (b >> 3) & 15, m = b & 7;
    float v = (e == 0) ? (float)m * 0.001953125f
                       : __uint_as_float(((e + 120u) << 23) | (m << 20));
    return s ? -v : v;
}

// ---------- fp4 e2m1 decode: dword of 8 nibbles -> ae[2] (even feats), ao[2] (odd) ----------
// mag LUT (fp8 e4m3 bytes): 0,0.5,1,1.5,2,3,4,6 -> 00,30,38,3C,40,44,48,4C

__device__ inline void accf4(f32x2* ae, f32x2* ao, unsigned d) {
#if __has_builtin(__builtin_amdgcn_cvt_pk_f32_fp8) && __has_builtin(__builtin_amdgcn_perm)
    unsigned lo8 = __builtin_amdgcn_perm(0x4C484440u, 0x3C383000u, d & 0x07070707u)
                 | ((d & 0x08080808u) << 4);
    unsigned hi8 = __builtin_amdgcn_perm(0x4C484440u, 0x3C383000u, (d >> 4) & 0x07070707u)
                 | (d & 0x80808080u);
    ae[0] += __builtin_amdgcn_cvt_pk_f32_fp8((int)lo8, false);
    ae[1] += __builtin_amdgcn_cvt_pk_f32_fp8((int)lo8, true);
    ao[0] += __builtin_amdgcn_cvt_pk_f32_fp8((int)hi8, false);
    ao[1] += __builtin_amdgcn_cvt_pk_f32_fp8((int)hi8, true);
#else
    #pragma unroll
    for (int i = 0; i < 4; ++i) {
        unsigned by = (d >> (8 * i)) & 0xFFu;
        unsigned ln = by & 7u, hn = (by >> 4) & 7u;
        float lv = (ln < 2) ? (float)ln * 0.5f : 0.5f * (float)(1 << ((ln >> 1) - 1)) * (2 + (ln & 1));
        float hv = (hn < 2) ? (float)hn * 0.5f : 0.5f * (float)(1 << ((hn >> 1) - 1)) * (2 + (hn & 1));
        if (by & 8u) lv = -lv;
        if (by & 0x80u) hv = -hv;
        ae[i >> 1][i & 1] += lv;
        ao[i >> 1][i & 1] += hv;
    }
#endif
}

// ---------- fp4 encode: f32 -> nibble (RNE over the e2m1 grid) ----------

__device__ inline unsigned fp4n(float v) {
    unsigned s = (__float_as_uint(v) >> 28) & 8u;
    float x = fabsf(v);
    unsigned n = (unsigned)(x >= 0.25f) + (x >= 0.75f) + (x >= 1.25f) + (x >= 1.75f)
               + (x >= 2.5f) + (x >= 3.5f) + (x >= 5.0f);
    return s | n;
}

__device__ inline unsigned short f2bf(float x) {
    unsigned u = __float_as_uint(x);
    return (unsigned short)((u + 0x7FFF + ((u >> 16) & 1)) >> 16);
}

// ---------- setup: Wc/bc, Wfrag, gcur, dummy rows — one kernel ----------

__global__ void k_setup(const float* __restrict__ W_emb, const float* __restrict__ b_emb,
                        const float* __restrict__ W1, const float* __restrict__ W2,
                        const float* __restrict__ W3, const float* __restrict__ W4,
                        float* __restrict__ Wc, float* __restrict__ bc,
                        unsigned short* __restrict__ Wfrag, int* __restrict__ gcur,
                        unsigned* __restrict__ ta, unsigned* __restrict__ tb) {
    int blk = blockIdx.x, t = threadIdx.x;
    if (blk == 0) {
        for (int i = t; i < 32 * 64; i += 256) {
            int a = i / 64, b = i % 64;
            float acc = 0.f;
            for (int k = 0; k < 64; ++k) acc += W_emb[a * 64 + k] * W1[k * 64 + b];
            Wc[i] = acc;
        }
        if (t < 64) {
            float acc = 0.f;
            for (int k = 0; k < 64; ++k) acc += b_emb[k] * W1[k * 64 + t];
            bc[t] = acc;
        }
    } else if (blk <= 3) {
        const float* W = (blk == 1) ? W2 : (blk == 2) ? W3 : W4;
        unsigned short* dst = Wfrag + (size_t)(blk - 1) * 4096;
        for (int i = 0; i < 16; ++i) {
            int flat = t * 16 + i;
            int j = flat & 7, lane = (flat >> 3) & 63, mt = (flat >> 9) & 3, kt = flat >> 11;
            int m = mt * 16 + (lane & 15);
            int k = kt * 32 + ((lane >> 4) << 3) + j;
            dst[flat] = f2bf(W[k * 64 + m]);
        }
    } else {
        for (int b = t; b < NBKT; b += 256) gcur[b] = b * CAP;
        if (t < 8) {
            size_t o = (size_t)N_NODES * 8 + t;
            ta[o] = 0; tb[o] = 0;
        }
    }
}

// ---------- Pass A: bin edges by dst>>8, per-wave LDS histograms ----------

__global__ void __launch_bounds__(512) k_bucket(const int* __restrict__ ei,
                                                int* __restrict__ gcur,
                                                int* __restrict__ ebuf) {
    __shared__ int cnt[8][NBKT];
    __shared__ int base[8][NBKT];
    int t = threadIdx.x, w = t >> 6;
    for (int i = t; i < 8 * NBKT; i += 512) ((int*)cnt)[i] = 0;
    __syncthreads();
    int e0 = blockIdx.x * EPB + t;
    int sv[32], dv[32];
    #pragma unroll
    for (int j = 0; j < 32; ++j) {
        int e = e0 + j * 512;
        if (e < N_EDGES) {
            sv[j] = ei[e];
            dv[j] = ei[N_EDGES + e];
            atomicAdd(&cnt[w][dv[j] >> 8], 1);
        } else dv[j] = -1;
    }
    __syncthreads();
    for (int b = t; b < NBKT; b += 512) {
        int tot = 0, c[8];
        #pragma unroll
        for (int ww = 0; ww < 8; ++ww) { c[ww] = cnt[ww][b]; tot += c[ww]; }
        int g = tot ? atomicAdd(&gcur[b], tot) : 0;
        #pragma unroll
        for (int ww = 0; ww < 8; ++ww) { base[ww][b] = g; g += c[ww]; cnt[ww][b] = 0; }
    }
    __syncthreads();
    #pragma unroll
    for (int j = 0; j < 32; ++j) {
        if (dv[j] >= 0) {
            int b = dv[j] >> 8;
            int r = atomicAdd(&cnt[w][b], 1);
            ebuf[base[w][b] + r] = (sv[j] << 8) | (dv[j] & 255);
        }
    }
}

// ---------- Pass B: per-bucket histogram -> rc/dis, 8-aligned col, pad-gap dummies ----------

__global__ void __launch_bounds__(256) k_fill2(const int* __restrict__ ebuf,
                                               const int* __restrict__ gcur,
                                               int2* __restrict__ rc,
                                               float* __restrict__ dis,
                                               int* __restrict__ col) {
    __shared__ int cnt[256];
    __shared__ int sc[256];
    __shared__ int exs[256];
    __shared__ int cur[256];
    int b = blockIdx.x, t = threadIdx.x;
    int n0 = b * 256;
    int nrec = gcur[b] - b * CAP;
    const int* eb = ebuf + (size_t)b * CAP;
    int* cw = col + (size_t)b * CAP;
    cnt[t] = 0; cur[t] = 0;
    __syncthreads();
    for (int i = t; i < nrec; i += 256)
        atomicAdd(&cnt[eb[i] & 255], 1);
    __syncthreads();
    int c0 = cnt[t];
    int a8 = (c0 + 7) & ~7;
    sc[t] = a8; __syncthreads();
    for (int off = 1; off < 256; off <<= 1) {
        int u = (t >= off) ? sc[t - off] : 0;
        __syncthreads();
        sc[t] += u;
        __syncthreads();
    }
    int myex = sc[t] - a8;
    exs[t] = myex;
    int n = n0 + t;
    if (n < N_NODES) {
        rc[n] = make_int2(b * CAP + myex, c0);
        dis[n] = rsqrtf((float)(c0 + 1));
    }
    for (int i = myex + c0; i < myex + a8; ++i) cw[i] = N_NODES;
    __syncthreads();
    for (int i = t; i < nrec; i += 256) {
        int rec = eb[i];
        int dl = rec & 255;
        cw[exs[dl] + atomicAdd(&cur[dl], 1)] = rec >> 8;
    }
}

// ---------- layer-1 matmul -> fp4 table (nibble-packed, 32B rows) ----------

__global__ void __launch_bounds__(256) k_mm1(const float* __restrict__ inp,
                                             const float* __restrict__ W,
                                             const float* __restrict__ bias,
                                             const float* __restrict__ dis,
                                             unsigned char* __restrict__ T) {
    __shared__ float Wl[32][64];
    __shared__ float hs[16][32];
    int t = threadIdx.x;
    for (int i = t; i < 32 * 64; i += 256) Wl[i / 64][i % 64] = W[i];
    int row0 = blockIdx.x * 16;
    for (int i = t; i < 16 * 32; i += 256) {
        int r = row0 + i / 32, k = i % 32;
        hs[i / 32][k] = inp[(size_t)r * 32 + k];
    }
    __syncthreads();
    int c = t & 63, rg = t >> 6;
    float a0 = 0, a1 = 0, a2 = 0, a3 = 0;
    #pragma unroll 4
    for (int k = 0; k < 32; ++k) {
        float wv = Wl[k][c];
        a0 += hs[rg * 4 + 0][k] * wv;
        a1 += hs[rg * 4 + 1][k] * wv;
        a2 += hs[rg * 4 + 2][k] * wv;
        a3 += hs[rg * 4 + 3][k] * wv;
    }
    float bv = bias[c];
    int r = row0 + rg * 4;
    unsigned n0 = fp4n(FP4_SCALE * dis[r + 0] * (a0 + bv));
    unsigned n1 = fp4n(FP4_SCALE * dis[r + 1] * (a1 + bv));
    unsigned n2 = fp4n(FP4_SCALE * dis[r + 2] * (a2 + bv));
    unsigned n3 = fp4n(FP4_SCALE * dis[r + 3] * (a3 + bv));
    unsigned p0 = __shfl_xor(n0, 1), p1 = __shfl_xor(n1, 1);
    unsigned p2 = __shfl_xor(n2, 1), p3 = __shfl_xor(n3, 1);
    if ((c & 1) == 0) {
        size_t boff = (size_t)(c >> 1);
        T[(size_t)(r + 0) * 32 + boff] = (unsigned char)(n0 | (p0 << 4));
        T[(size_t)(r + 1) * 32 + boff] = (unsigned char)(n1 | (p1 << 4));
        T[(size_t)(r + 2) * 32 + boff] = (unsigned char)(n2 | (p2 << 4));
        T[(size_t)(r + 3) * 32 + boff] = (unsigned char)(n3 | (p3 << 4));
    }
}

// ---------- FUSED AGG + COMBINE (fp4): 32 rows/block, 4 waves ----------
// agg phase: 8 rows/wave x 8 feature-dwords, 8-deep pipelined gathers;
// then h = relu(dis/S*agg + b) -> LDS -> MFMA h@Wn -> next fp4 table.
// LAST: write relu'd h (bf16) to hout instead.

template<bool LAST>
__global__ void __launch_bounds__(256, 8) k_aggc(const unsigned* __restrict__ tph,
                                                 const int2* __restrict__ rc,
                                                 const int* __restrict__ col,
                                                 const float* __restrict__ dis,
                                                 const float* __restrict__ bias,
                                                 const unsigned short* __restrict__ Wfrag,
                                                 unsigned char* __restrict__ Tn,
                                                 unsigned short* __restrict__ hout) {
    __shared__ unsigned short h_lds[32][72];
    int t = threadIdx.x;
    int rowbase = blockIdx.x * 32;
    int row = rowbase + (t >> 3);
    int sl = t & 7;
    f32x2 ae[2] = {{0.f, 0.f}, {0.f, 0.f}};
    f32x2 ao[2] = {{0.f, 0.f}, {0.f, 0.f}};
    accf4(ae, ao, tph[(size_t)row * 8 + sl]);          // self-loop term
    int2 r = rc[row];
    int nit = (r.y + 7) >> 3;                          // 8-edge iterations
    const int* cp = col + r.x;
    if (nit > 0) {
        int4 c0 = *(const int4*)(cp + 0);
        int4 c1 = *(const int4*)(cp + 4);
        for (int it = 1; it < nit; ++it) {
            unsigned v0 = tph[(size_t)c0.x * 8 + sl];
            unsigned v1 = tph[(size_t)c0.y * 8 + sl];
            unsigned v2 = tph[(size_t)c0.z * 8 + sl];
            unsigned v3 = tph[(size_t)c0.w * 8 + sl];
            unsigned v4 = tph[(size_t)c1.x * 8 + sl];
            unsigned v5 = tph[(size_t)c1.y * 8 + sl];
            unsigned v6 = tph[(size_t)c1.z * 8 + sl];
            unsigned v7 = tph[(size_t)c1.w * 8 + sl];
            const int* np = cp + it * 8;               // prefetch next 8 cols
            c0 = *(const int4*)(np + 0);
            c1 = *(const int4*)(np + 4);
            accf4(ae, ao, v0); accf4(ae, ao, v1); accf4(ae, ao, v2); accf4(ae, ao, v3);
            accf4(ae, ao, v4); accf4(ae, ao, v5); accf4(ae, ao, v6); accf4(ae, ao, v7);
        }
        unsigned v0 = tph[(size_t)c0.x * 8 + sl];
        unsigned v1 = tph[(size_t)c0.y * 8 + sl];
        unsigned v2 = tph[(size_t)c0.z * 8 + sl];
        unsigned v3 = tph[(size_t)c0.w * 8 + sl];
        unsigned v4 = tph[(size_t)c1.x * 8 + sl];
        unsigned v5 = tph[(size_t)c1.y * 8 + sl];
        unsigned v6 = tph[(size_t)c1.z * 8 + sl];
        unsigned v7 = tph[(size_t)c1.w * 8 + sl];
        accf4(ae, ao, v0); accf4(ae, ao, v1); accf4(ae, ao, v2); accf4(ae, ao, v3);
        accf4(ae, ao, v4); accf4(ae, ao, v5); accf4(ae, ao, v6); accf4(ae, ao, v7);
    }
    // h = relu(dis/S * agg + bias), features sl*8 .. sl*8+7 (even in ae, odd in ao)
    float ds = dis[row] * FP4_INV;
    int f0 = sl * 8;
    float h0 = fmaxf(ds * ae[0].x + bias[f0 + 0], 0.f);
    float h1 = fmaxf(ds * ao[0].x + bias[f0 + 1], 0.f);
    float h2 = fmaxf(ds * ae[0].y + bias[f0 + 2], 0.f);
    float h3 = fmaxf(ds * ao[0].y + bias[f0 + 3], 0.f);
    float h4 = fmaxf(ds * ae[1].x + bias[f0 + 4], 0.f);
    float h5 = fmaxf(ds * ao[1].x + bias[f0 + 5], 0.f);
    float h6 = fmaxf(ds * ae[1].y + bias[f0 + 6], 0.f);
    float h7 = fmaxf(ds * ao[1].y + bias[f0 + 7], 0.f);
    uint4 o;
    o.x = (unsigned)f2bf(h0) | ((unsigned)f2bf(h1) << 16);
    o.y = (unsigned)f2bf(h2) | ((unsigned)f2bf(h3) << 16);
    o.z = (unsigned)f2bf(h4) | ((unsigned)f2bf(h5) << 16);
    o.w = (unsigned)f2bf(h6) | ((unsigned)f2bf(h7) << 16);
    if (LAST) {
        *(uint4*)(hout + (size_t)row * 64 + f0) = o;
        return;
    }
    *(uint4*)&h_lds[row - rowbase][f0] = o;
    __syncthreads();
    // MFMA: wave w handles row-group (w&1), mt-tiles {2*(w>>1), 2*(w>>1)+1}
    int w = t >> 6, l = t & 63;
    int rg = w & 1, mt0 = (w >> 1) << 1;
    f32x4 acc[2] = {{0, 0, 0, 0}, {0, 0, 0, 0}};
    const bf16x8* wf = (const bf16x8*)Wfrag;
    #pragma unroll
    for (int kt = 0; kt < 2; ++kt) {
        bf16x8 bfr = *(const bf16x8*)&h_lds[rg * 16 + (l & 15)][kt * 32 + ((l >> 4) << 3)];
        #pragma unroll
        for (int mi = 0; mi < 2; ++mi) {
            bf16x8 afr = wf[(kt * 4 + mt0 + mi) * 64 + l];
            acc[mi] = __builtin_amdgcn_mfma_f32_16x16x32_bf16(afr, bfr, acc[mi], 0, 0, 0);
        }
    }
    int hrow = rowbase + rg * 16 + (l & 15);
    float sc2 = FP4_SCALE * dis[hrow];
    #pragma unroll
    for (int mi = 0; mi < 2; ++mi) {
        int colbase = (mt0 + mi) * 16 + ((l >> 4) << 2);
        unsigned short v = (unsigned short)(fp4n(sc2 * acc[mi][0])
                           | (fp4n(sc2 * acc[mi][1]) << 4)
                           | (fp4n(sc2 * acc[mi][2]) << 8)
                           | (fp4n(sc2 * acc[mi][3]) << 12));
        *(unsigned short*)(Tn + (size_t)hrow * 32 + (colbase >> 1)) = v;
    }
}

// ---------- pool (h pre-activated) + MLP head + log_softmax ----------

__global__ void __launch_bounds__(256) k_poolhead(const unsigned short* __restrict__ h,
                                                  const int* __restrict__ batch,
                                                  const float* __restrict__ Wr1, const float* __restrict__ br1,
                                                  const float* __restrict__ Wr2, const float* __restrict__ br2,
                                                  const float* __restrict__ Wr3, const float* __restrict__ br3,
                                                  float* __restrict__ out) {
    __shared__ float part[4][64];
    __shared__ float p[64], r1[32], r2[16], lg[10];
    __shared__ int seg[2];
    int g = blockIdx.x, t = threadIdx.x;
    if (t < 2) {
        int key = g + t;
        int lo = 0, hi = N_NODES;
        while (lo < hi) { int m = (lo + hi) >> 1; if (batch[m] < key) lo = m + 1; else hi = m; }
        seg[t] = lo;
    }
    __syncthreads();
    int start = seg[0], end = seg[1];
    int w = t >> 6, grp = (t >> 4) & 3, sl = t & 15;
    float a[4] = {0.f, 0.f, 0.f, 0.f};
    for (int r = start + w * 4 + grp; r < end; r += 16) {
        ushort4 v = *(const ushort4*)(h + (size_t)r * 64 + sl * 4);
        a[0] += __uint_as_float((unsigned)v.x << 16);
        a[1] += __uint_as_float((unsigned)v.y << 16);
        a[2] += __uint_as_float((unsigned)v.z << 16);
        a[3] += __uint_as_float((unsigned)v.w << 16);
    }
    #pragma unroll
    for (int j = 0; j < 4; ++j) {
        a[j] += __shfl_xor(a[j], 16);
        a[j] += __shfl_xor(a[j], 32);
    }
    if (sl == (t & 63)) {
        #pragma unroll
        for (int j = 0; j < 4; ++j) part[w][sl * 4 + j] = a[j];
    }
    __syncthreads();
    if (t < 64) {
        float s = part[0][t] + part[1][t] + part[2][t] + part[3][t];
        float c = fmaxf((float)(end - start), 1.f);
        p[t] = s / c;
    }
    __syncthreads();
    if (t < 32) {
        float acc = br1[t];
        for (int k = 0; k < 64; ++k) acc += p[k] * Wr1[k * 32 + t];
        r1[t] = fmaxf(acc, 0.f);
    }
    __syncthreads();
    if (t < 16) {
        float acc = br2[t];
        for (int k = 0; k < 32; ++k) acc += r1[k] * Wr2[k * 16 + t];
        r2[t] = fmaxf(acc, 0.f);
    }
    __syncthreads();
    if (t < 10) {
        float acc = br3[t];
        for (int k = 0; k < 16; ++k) acc += r2[k] * Wr3[k * 10 + t];
        lg[t] = acc;
    }
    __syncthreads();
    if (t < 10) {
        float m = -1e30f;
        for (int j = 0; j < 10; ++j) m = fmaxf(m, lg[j]);
        float s = 0.f;
        for (int j = 0; j < 10; ++j) s += expf(lg[j] - m);
        out[g * 10 + t] = lg[t] - m - logf(s);
    }
}

extern "C" void kernel_launch(void* const* d_in, const int* in_sizes, int n_in,
                              void* d_out, int out_size, void* d_ws, size_t ws_size,
                              hipStream_t stream) {
    const float* x     = (const float*)d_in[0];
    const int*   ei    = (const int*)d_in[1];
    const int*   batch = (const int*)d_in[2];
    const float* W_emb = (const float*)d_in[4];
    const float* b_emb = (const float*)d_in[5];
    const float* W1    = (const float*)d_in[6];
    const float* b1    = (const float*)d_in[7];
    const float* W2    = (const float*)d_in[8];
    const float* b2    = (const float*)d_in[9];
    const float* W3    = (const float*)d_in[10];
    const float* b3    = (const float*)d_in[11];
    const float* W4    = (const float*)d_in[12];
    const float* b4    = (const float*)d_in[13];
    const float* Wr1   = (const float*)d_in[14];
    const float* br1   = (const float*)d_in[15];
    const float* Wr2   = (const float*)d_in[16];
    const float* br2   = (const float*)d_in[17];
    const float* Wr3   = (const float*)d_in[18];
    const float* br3   = (const float*)d_in[19];
    float* out = (float*)d_out;

    char* ws = (char*)d_ws;
    size_t off = 0;
    auto alloc = [&](size_t b) { char* p = ws + off; off += (b + 511) & ~(size_t)511; return p; };
    size_t TBYTES = (size_t)(N_NODES + 1) * 32;
    int*   col    = (int*)  alloc((size_t)NBKT * CAP * 4);     // 16.4 MB
    int*   ebuf   = (int*)  alloc((size_t)NBKT * CAP * 4);     // later reused as hout
    unsigned char* Ta = (unsigned char*)alloc(TBYTES);         // fp4 tables (+dummy row)
    unsigned char* Tb = (unsigned char*)alloc(TBYTES);
    int2*  rc     = (int2*) alloc((size_t)N_NODES * 8);
    float* dis    = (float*)alloc((size_t)N_NODES * 4);
    int*   gcur   = (int*)  alloc((size_t)NBKT * 4);
    float* Wc     = (float*)alloc(32 * 64 * 4);
    float* bc     = (float*)alloc(64 * 4);
    unsigned short* Wfrag = (unsigned short*)alloc(3 * 4096 * 2);

    unsigned short* hout = (unsigned short*)ebuf;    // alias: h lives where ebuf was

    k_setup<<<5, 256, 0, stream>>>(W_emb, b_emb, W1, W2, W3, W4, Wc, bc, Wfrag, gcur,
                                   (unsigned*)Ta, (unsigned*)Tb);
    k_bucket<<<NBLK_A, 512, 0, stream>>>(ei, gcur, ebuf);
    k_fill2<<<NBKT, 256, 0, stream>>>(ebuf, gcur, rc, dis, col);

    int nbm = N_NODES / 16;        // 6250
    int nba = N_NODES / 32;        // 3125

    k_mm1<<<nbm, 256, 0, stream>>>(x, Wc, bc, dis, Ta);

    // layers 1-3: fused agg+combine, ping-pong fp4 tables
    k_aggc<false><<<nba, 256, 0, stream>>>((const unsigned*)Ta, rc, col, dis, b1,
                                           Wfrag + 0 * 4096, Tb, nullptr);
    k_aggc<false><<<nba, 256, 0, stream>>>((const unsigned*)Tb, rc, col, dis, b2,
                                           Wfrag + 1 * 4096, Ta, nullptr);
    k_aggc<false><<<nba, 256, 0, stream>>>((const unsigned*)Ta, rc, col, dis, b3,
                                           Wfrag + 2 * 4096, Tb, nullptr);
    // layer 4: fused agg + bias/relu -> h
    k_aggc<true><<<nba, 256, 0, stream>>>((const unsigned*)Tb, rc, col, dis, b4,
                                          nullptr, nullptr, hout);

    k_poolhead<<<N_GRAPHS, 256, 0, stream>>>(hout, batch, Wr1, br1, Wr2, br2, Wr3, br3, out);
}